// Round 1
// baseline (1066.880 us; speedup 1.0000x reference)
//
#include <hip/hip_runtime.h>

// ============================================================================
// MultiHeadCrossAttention on MI355X (gfx950)
//   B=2, SQ=SK=2048, H=16, D=64, EMB=CTX=INNER=1024, fp32 in/out.
//   Tolerance is 2% of |ref|max -> bf16 compute with fp32 accumulation.
//
// Pipeline:
//   1. cvt fp32->bf16: emb, context, Wq, Wk, Wv, Wu into d_ws
//   2. gemm_bt (MFMA 16x16x32 bf16, 128x128 tile): q_raw, k_raw, v
//   3. layernorm over D=64 head chunks on q, k (in place, bf16)
//   4. scalar flash attention (online softmax), 32q x 64k tiles
//   5. gemm_bt mode 1: d_out = ao @ Wu^T + bu (fp32 out)
//
// Workspace layout (shorts): emb(4M) ctx(4M) Wq Wk Wv Wu(1M each) q k v ao(4M each)
//   total 28M elems = 56 MB.
// ============================================================================

typedef __attribute__((ext_vector_type(8))) short bf16x8;
typedef __attribute__((ext_vector_type(4))) short bf16x4;
typedef __attribute__((ext_vector_type(4))) float f32x4;

__device__ __forceinline__ float b2f(short h){
  unsigned int u = ((unsigned int)(unsigned short)h) << 16;
  float f;
  __builtin_memcpy(&f, &u, 4);
  return f;
}
__device__ __forceinline__ short f2b(float f){
  unsigned int u;
  __builtin_memcpy(&u, &f, 4);
  u += 0x7fffu + ((u >> 16) & 1u);   // round-to-nearest-even
  return (short)(u >> 16);
}

// ---------------------------------------------------------------------------
// fp32 -> bf16 elementwise convert (n multiple of 4)
// ---------------------------------------------------------------------------
__global__ __launch_bounds__(256) void cvt_kernel(const float* __restrict__ in,
                                                  short* __restrict__ out, int n){
  int i = (blockIdx.x * 256 + threadIdx.x) * 4;
  if (i >= n) return;
  f32x4 v = *(const f32x4*)(in + i);
  bf16x4 o;
  o[0] = f2b(v[0]); o[1] = f2b(v[1]); o[2] = f2b(v[2]); o[3] = f2b(v[3]);
  *(bf16x4*)(out + i) = o;
}

// ---------------------------------------------------------------------------
// C[M,N] = A[M,K] @ B[N,K]^T, bf16 inputs, fp32 accum. M=4096, N=K=1024.
// 128x128 block tile, 4 waves in 2x2, each wave 64x64 (4x4 MFMA tiles).
// mode 0: C -> bf16 (Ch). mode 1: C -> fp32 + bias[col] (Cf).
// MFMA 16x16x32 bf16 fragment layouts (HW-verified per guide):
//   A: lane holds A[m=lane&15][k=(lane>>4)*8 + j], j=0..7
//   B: lane holds B[n=lane&15][k=(lane>>4)*8 + j]   (B given as [N,K] row-major)
//   C/D: col = lane&15, row = (lane>>4)*4 + reg
// ---------------------------------------------------------------------------
__global__ __launch_bounds__(256) void gemm_bt_kernel(
    const short* __restrict__ A, const short* __restrict__ B,
    short* __restrict__ Ch, float* __restrict__ Cf,
    const float* __restrict__ bias, int mode)
{
  const int K = 1024, N = 1024;
  __shared__ short As[128 * 64];   // unpadded [row][k] (m97-proven layout)
  __shared__ short Bs[128 * 64];
  const int tid  = threadIdx.x;
  const int wave = tid >> 6, lane = tid & 63;
  const int quad = lane >> 4, r16 = lane & 15;
  const int wm = (wave >> 1) * 64, wn = (wave & 1) * 64;
  const int bm = blockIdx.y * 128, bn = blockIdx.x * 128;

  f32x4 acc[4][4];
#pragma unroll
  for (int i = 0; i < 4; i++)
#pragma unroll
    for (int j = 0; j < 4; j++)
      acc[i][j] = (f32x4){0.f, 0.f, 0.f, 0.f};

  const int srow = tid >> 3, sc8 = (tid & 7) * 8;   // staging: 16B chunks

  for (int k0 = 0; k0 < K; k0 += 64){
#pragma unroll
    for (int i = 0; i < 4; i++){
      int row = srow + 32 * i;
      *(bf16x8*)(&As[row * 64 + sc8]) =
          *(const bf16x8*)(A + (size_t)(bm + row) * K + k0 + sc8);
      *(bf16x8*)(&Bs[row * 64 + sc8]) =
          *(const bf16x8*)(B + (size_t)(bn + row) * K + k0 + sc8);
    }
    __syncthreads();
#pragma unroll
    for (int kk = 0; kk < 2; kk++){
      bf16x8 af[4], bq[4];
#pragma unroll
      for (int i = 0; i < 4; i++)
        af[i] = *(const bf16x8*)(&As[(wm + i*16 + r16) * 64 + kk*32 + quad*8]);
#pragma unroll
      for (int j = 0; j < 4; j++)
        bq[j] = *(const bf16x8*)(&Bs[(wn + j*16 + r16) * 64 + kk*32 + quad*8]);
#pragma unroll
      for (int i = 0; i < 4; i++)
#pragma unroll
        for (int j = 0; j < 4; j++)
          acc[i][j] = __builtin_amdgcn_mfma_f32_16x16x32_bf16(af[i], bq[j], acc[i][j], 0, 0, 0);
    }
    __syncthreads();
  }

#pragma unroll
  for (int i = 0; i < 4; i++){
#pragma unroll
    for (int j = 0; j < 4; j++){
      const int col = bn + wn + j*16 + r16;
#pragma unroll
      for (int t = 0; t < 4; t++){
        const size_t row = (size_t)(bm + wm + i*16 + quad*4 + t);
        const float v = acc[i][j][t];
        if (mode == 0) Ch[row * N + col] = f2b(v);
        else           Cf[row * N + col] = v + bias[col];
      }
    }
  }
}

// ---------------------------------------------------------------------------
// LayerNorm over contiguous 64-elem groups (head dim), bf16 in place.
// One wave per group, lane = dim index. 4 groups per 256-thread block.
// ---------------------------------------------------------------------------
__global__ __launch_bounds__(256) void ln_kernel(short* __restrict__ x,
                                                 const float* __restrict__ w,
                                                 const float* __restrict__ b){
  const int g = blockIdx.x * 4 + (threadIdx.x >> 6);
  const int lane = threadIdx.x & 63;
  const size_t idx = (size_t)g * 64 + lane;
  const float v = b2f(x[idx]);
  float s = v;
#pragma unroll
  for (int off = 32; off > 0; off >>= 1) s += __shfl_xor(s, off);
  const float mu = s * (1.f / 64.f);
  const float d = v - mu;
  float vs = d * d;
#pragma unroll
  for (int off = 32; off > 0; off >>= 1) vs += __shfl_xor(vs, off);
  const float var = vs * (1.f / 64.f);
  const float y = d * rsqrtf(var + 1e-5f) * w[lane] + b[lane];
  x[idx] = f2b(y);
}

// ---------------------------------------------------------------------------
// Scalar flash attention. Grid (64 qtiles, 16 heads, 2 batch), 256 threads.
// Q-tile 32 queries, key tiles of 64. Online softmax (running m, l).
// Thread t: tq = t>>3 (query 0..31), tc = t&7.
//   S phase : computes S[tq][tc + 8*it], it=0..7 (dot64 via f32x4 from LDS)
//   PV phase: accumulates O[tq][tc*8 .. tc*8+7] in registers
// LDS rows padded to stride 68 floats (bank-conflict-free patterns verified
// by hand: frag/row reads land on distinct 4-bank groups or broadcast).
// ---------------------------------------------------------------------------
#define FA_PAD 68
__global__ __launch_bounds__(256) void flash_attn_kernel(
    const short* __restrict__ Q, const short* __restrict__ K,
    const short* __restrict__ V, short* __restrict__ O)
{
  __shared__ float Qs[32 * FA_PAD];
  __shared__ float Ks[64 * FA_PAD];
  __shared__ float Vs[64 * FA_PAD];
  __shared__ float Sb[32 * FA_PAD];
  __shared__ float mS[32], lS[32], aS[32];
  __shared__ float red[32 * 8];

  const int tid = threadIdx.x;
  const int qb = blockIdx.x, h = blockIdx.y, b = blockIdx.z;
  const size_t base = ((size_t)b * 2048) * 1024 + (size_t)h * 64;  // + s*1024 + d
  const int q0 = qb * 32;

  {   // stage Q tile: 32 rows x 64 dims, one 8-elem chunk per thread
    const int row = tid >> 3, c8 = (tid & 7) * 8;
    bf16x8 hv = *(const bf16x8*)(Q + base + (size_t)(q0 + row) * 1024 + c8);
#pragma unroll
    for (int i = 0; i < 8; i++) Qs[row * FA_PAD + c8 + i] = b2f(hv[i]);
  }
  if (tid < 32){ mS[tid] = -1e30f; lS[tid] = 0.f; }
  __syncthreads();

  float o[8] = {0.f, 0.f, 0.f, 0.f, 0.f, 0.f, 0.f, 0.f};
  const int tq = tid >> 3, tc = tid & 7;

  for (int kt = 0; kt < 2048 / 64; kt++){
    // ---- stage K,V tile (64x64), 2 chunks each per thread ----
#pragma unroll
    for (int i = 0; i < 2; i++){
      const int c = tid + 256 * i;
      const int row = c >> 3, c8 = (c & 7) * 8;
      const size_t gofs = base + (size_t)(kt * 64 + row) * 1024 + c8;
      bf16x8 hk = *(const bf16x8*)(K + gofs);
      bf16x8 hv = *(const bf16x8*)(V + gofs);
#pragma unroll
      for (int j = 0; j < 8; j++){
        Ks[row * FA_PAD + c8 + j] = b2f(hk[j]);
        Vs[row * FA_PAD + c8 + j] = b2f(hv[j]);
      }
    }
    __syncthreads();                                   // B1

    // ---- S = (Q K^T) * scale, track per-thread partial max ----
    float pm = -1e30f;
    const f32x4* qr = (const f32x4*)(Qs + tq * FA_PAD);
#pragma unroll
    for (int it = 0; it < 8; it++){
      const int j = tc + it * 8;
      const f32x4* kr = (const f32x4*)(Ks + j * FA_PAD);
      f32x4 a4 = (f32x4){0.f, 0.f, 0.f, 0.f};
#pragma unroll
      for (int d4 = 0; d4 < 16; d4++) a4 += qr[d4] * kr[d4];
      const float s = (a4[0] + a4[1] + a4[2] + a4[3]) * 0.125f;
      Sb[tq * FA_PAD + j] = s;
      pm = fmaxf(pm, s);
    }
    red[tq * 8 + tc] = pm;
    __syncthreads();                                   // B2

    if (tid < 32){
      float m_old = mS[tid], mn = m_old;
#pragma unroll
      for (int c = 0; c < 8; c++) mn = fmaxf(mn, red[tid * 8 + c]);
      mS[tid] = mn;
      aS[tid] = __expf(m_old - mn);
    }
    __syncthreads();                                   // B3

    // ---- P = exp(S - m), partial row sums ----
    const float mq = mS[tq];
    float ps = 0.f;
#pragma unroll
    for (int it = 0; it < 8; it++){
      const int j = tc + it * 8;
      const float p = __expf(Sb[tq * FA_PAD + j] - mq);
      Sb[tq * FA_PAD + j] = p;
      ps += p;
    }
    red[tq * 8 + tc] = ps;
    __syncthreads();                                   // B4

    if (tid < 32){
      float s = 0.f;
#pragma unroll
      for (int c = 0; c < 8; c++) s += red[tid * 8 + c];
      lS[tid] = lS[tid] * aS[tid] + s;
    }

    // ---- O = alpha*O + P V ----
    const float alpha = aS[tq];
#pragma unroll
    for (int i = 0; i < 8; i++) o[i] *= alpha;
    for (int j = 0; j < 64; j++){
      const float p = Sb[tq * FA_PAD + j];
      const float* vr = Vs + j * FA_PAD + tc * 8;
#pragma unroll
      for (int i = 0; i < 8; i++) o[i] += p * vr[i];
    }
    __syncthreads();                                   // B5
  }

  const float inv = 1.f / lS[tq];
  bf16x8 pack;
#pragma unroll
  for (int i = 0; i < 8; i++) pack[i] = f2b(o[i] * inv);
  *(bf16x8*)(O + base + (size_t)(q0 + tq) * 1024 + tc * 8) = pack;
}

// ---------------------------------------------------------------------------
extern "C" void kernel_launch(void* const* d_in, const int* in_sizes, int n_in,
                              void* d_out, int out_size, void* d_ws, size_t ws_size,
                              hipStream_t stream) {
  const float* emb  = (const float*)d_in[0];
  const float* ctx  = (const float*)d_in[1];
  const float* Wq   = (const float*)d_in[2];
  const float* Wk   = (const float*)d_in[3];
  const float* Wv   = (const float*)d_in[4];
  const float* Wu   = (const float*)d_in[5];
  const float* bu   = (const float*)d_in[6];
  const float* qn_w = (const float*)d_in[7];
  const float* qn_b = (const float*)d_in[8];
  const float* kn_w = (const float*)d_in[9];
  const float* kn_b = (const float*)d_in[10];
  float* out = (float*)d_out;

  const size_t BIG = (size_t)4096 * 1024;   // 4M elems
  const size_t WSZ = (size_t)1024 * 1024;   // 1M elems
  short* ws   = (short*)d_ws;
  short* embh = ws;
  short* ctxh = embh + BIG;
  short* Wqh  = ctxh + BIG;
  short* Wkh  = Wqh + WSZ;
  short* Wvh  = Wkh + WSZ;
  short* Wuh  = Wvh + WSZ;
  short* qh   = Wuh + WSZ;
  short* kh   = qh + BIG;
  short* vh   = kh + BIG;
  short* aoh  = vh + BIG;

  cvt_kernel<<<4096, 256, 0, stream>>>(emb, embh, (int)BIG);
  cvt_kernel<<<4096, 256, 0, stream>>>(ctx, ctxh, (int)BIG);
  cvt_kernel<<<1024, 256, 0, stream>>>(Wq, Wqh, (int)WSZ);
  cvt_kernel<<<1024, 256, 0, stream>>>(Wk, Wkh, (int)WSZ);
  cvt_kernel<<<1024, 256, 0, stream>>>(Wv, Wvh, (int)WSZ);
  cvt_kernel<<<1024, 256, 0, stream>>>(Wu, Wuh, (int)WSZ);

  dim3 gg(8, 32);   // N/128, M/128
  gemm_bt_kernel<<<gg, 256, 0, stream>>>(embh, Wqh, qh, nullptr, nullptr, 0);
  gemm_bt_kernel<<<gg, 256, 0, stream>>>(ctxh, Wkh, kh, nullptr, nullptr, 0);
  gemm_bt_kernel<<<gg, 256, 0, stream>>>(ctxh, Wvh, vh, nullptr, nullptr, 0);

  ln_kernel<<<16384, 256, 0, stream>>>(qh, qn_w, qn_b);
  ln_kernel<<<16384, 256, 0, stream>>>(kh, kn_w, kn_b);

  dim3 ga(64, 16, 2);   // qtile, head, batch (x fastest -> K/V L2 reuse)
  flash_attn_kernel<<<ga, 256, 0, stream>>>(qh, kh, vh, aoh);

  gemm_bt_kernel<<<gg, 256, 0, stream>>>(aoh, Wuh, nullptr, out, bu, 1);
}

// Round 2
// 337.566 us; speedup vs baseline: 3.1605x; 3.1605x over previous
//
#include <hip/hip_runtime.h>

// ============================================================================
// MultiHeadCrossAttention on MI355X (gfx950) — round 1: MFMA flash attention
//   B=2, SQ=SK=2048, H=16, D=64, EMB=CTX=INNER=1024, fp32 in/out.
//
// Pipeline:
//   1. cvt fp32->bf16: emb, context, Wq, Wk, Wv, Wu
//   2. gemm_bt (MFMA 16x16x32 bf16, 128x128 tile, global_load_lds staging):
//        q = emb@Wq^T [4096,1024], k = ctx@Wk^T [4096,1024],
//        vT = Wv@ctx^T [1024,4096]  (V produced PRE-TRANSPOSED)
//   3. layernorm over D=64 head chunks on q, k (in place, bf16)
//   4. MFMA flash attention, fixed-max softmax (LN bounds |S|<=8), l via
//      ones-column of V (no shuffles, no rescale)
//   5. gemm_bt mode 1: d_out = ao @ Wu^T + bu (fp32 out)
// ============================================================================

typedef __attribute__((ext_vector_type(8))) short bf16x8;
typedef __attribute__((ext_vector_type(4))) short bf16x4;
typedef __attribute__((ext_vector_type(4))) float f32x4;

typedef __attribute__((address_space(1))) const void cg_void;
typedef __attribute__((address_space(3))) void lds_void_t;

__device__ __forceinline__ void gl_lds16(const void* g, void* l){
  __builtin_amdgcn_global_load_lds((cg_void*)g, (lds_void_t*)l, 16, 0, 0);
}

__device__ __forceinline__ float b2f(short h){
  unsigned int u = ((unsigned int)(unsigned short)h) << 16;
  float f;
  __builtin_memcpy(&f, &u, 4);
  return f;
}
__device__ __forceinline__ short f2b(float f){
  unsigned int u;
  __builtin_memcpy(&u, &f, 4);
  u += 0x7fffu + ((u >> 16) & 1u);   // round-to-nearest-even
  return (short)(u >> 16);
}

// ---------------------------------------------------------------------------
// fp32 -> bf16 elementwise convert (n multiple of 4)
// ---------------------------------------------------------------------------
__global__ __launch_bounds__(256) void cvt_kernel(const float* __restrict__ in,
                                                  short* __restrict__ out, int n){
  int i = (blockIdx.x * 256 + threadIdx.x) * 4;
  if (i >= n) return;
  f32x4 v = *(const f32x4*)(in + i);
  bf16x4 o;
  o[0] = f2b(v[0]); o[1] = f2b(v[1]); o[2] = f2b(v[2]); o[3] = f2b(v[3]);
  *(bf16x4*)(out + i) = o;
}

// ---------------------------------------------------------------------------
// C[M,N] = A[M,K] @ B[N,K]^T, bf16 in, fp32 accum. K=1024 fixed, N a param,
// M from gridDim.y*128. 128x128 tile, 4 waves 2x2, wave does 64x64.
// Staging via global_load_lds width=16 (m97 pattern).
// mode 0: C -> bf16 (Ch). mode 1: C -> fp32 + bias[col] (Cf).
// ---------------------------------------------------------------------------
__global__ __launch_bounds__(256) void gemm_bt_kernel(
    const short* __restrict__ A, const short* __restrict__ B,
    short* __restrict__ Ch, float* __restrict__ Cf,
    const float* __restrict__ bias, int N, int mode)
{
  const int K = 1024;
  __shared__ short As[128 * 64];
  __shared__ short Bs[128 * 64];
  const int tid  = threadIdx.x;
  const int wave = tid >> 6, lane = tid & 63;
  const int quad = lane >> 4, r16 = lane & 15;
  const int wm = (wave >> 1) * 64, wn = (wave & 1) * 64;
  const int bm = blockIdx.y * 128, bn = blockIdx.x * 128;

  f32x4 acc[4][4];
#pragma unroll
  for (int i = 0; i < 4; i++)
#pragma unroll
    for (int j = 0; j < 4; j++)
      acc[i][j] = (f32x4){0.f, 0.f, 0.f, 0.f};

  // staging: lane l of wave w covers row (w*8 + (l>>3) + 32*i), col (l&7)*8
  const size_t arow = (size_t)(bm + wave * 8 + (lane >> 3)) * K + (lane & 7) * 8;
  const size_t brow = (size_t)(bn + wave * 8 + (lane >> 3)) * K + (lane & 7) * 8;

  for (int k0 = 0; k0 < K; k0 += 64){
#pragma unroll
    for (int i = 0; i < 4; i++){
      gl_lds16(A + arow + (size_t)32 * i * K + k0, &As[wave * 512 + i * 2048]);
      gl_lds16(B + brow + (size_t)32 * i * K + k0, &Bs[wave * 512 + i * 2048]);
    }
    __syncthreads();
#pragma unroll
    for (int kk = 0; kk < 2; kk++){
      bf16x8 af[4], bq[4];
#pragma unroll
      for (int i = 0; i < 4; i++)
        af[i] = *(const bf16x8*)(&As[(wm + i*16 + r16) * 64 + kk*32 + quad*8]);
#pragma unroll
      for (int j = 0; j < 4; j++)
        bq[j] = *(const bf16x8*)(&Bs[(wn + j*16 + r16) * 64 + kk*32 + quad*8]);
#pragma unroll
      for (int i = 0; i < 4; i++)
#pragma unroll
        for (int j = 0; j < 4; j++)
          acc[i][j] = __builtin_amdgcn_mfma_f32_16x16x32_bf16(af[i], bq[j], acc[i][j], 0, 0, 0);
    }
    __syncthreads();
  }

#pragma unroll
  for (int i = 0; i < 4; i++){
#pragma unroll
    for (int j = 0; j < 4; j++){
      const int col = bn + wn + j*16 + r16;
#pragma unroll
      for (int t = 0; t < 4; t++){
        const size_t row = (size_t)(bm + wm + i*16 + quad*4 + t);
        const float v = acc[i][j][t];
        if (mode == 0) Ch[row * N + col] = f2b(v);
        else           Cf[row * N + col] = v + bias[col];
      }
    }
  }
}

// ---------------------------------------------------------------------------
// LayerNorm over contiguous 64-elem groups, bf16 in place. Wave per group.
// ---------------------------------------------------------------------------
__global__ __launch_bounds__(256) void ln_kernel(short* __restrict__ x,
                                                 const float* __restrict__ w,
                                                 const float* __restrict__ b){
  const int g = blockIdx.x * 4 + (threadIdx.x >> 6);
  const int lane = threadIdx.x & 63;
  const size_t idx = (size_t)g * 64 + lane;
  const float v = b2f(x[idx]);
  float s = v;
#pragma unroll
  for (int off = 32; off > 0; off >>= 1) s += __shfl_xor(s, off);
  const float mu = s * (1.f / 64.f);
  const float d = v - mu;
  float vs = d * d;
#pragma unroll
  for (int off = 32; off > 0; off >>= 1) vs += __shfl_xor(vs, off);
  const float var = vs * (1.f / 64.f);
  const float y = d * rsqrtf(var + 1e-5f) * w[lane] + b[lane];
  x[idx] = f2b(y);
}

// ---------------------------------------------------------------------------
// MFMA flash attention, no running max (LN bounds |S*scale| <= 8).
//   Grid (32 qblocks, 16 heads, 2 batch), 256 threads = 4 waves.
//   Block: 64 queries; wave: 16 queries. K-tiles of 64 keys.
//   S = Q·K^T  (Q A-frags in registers, K staged [key][d] in LDS)
//   P = exp2(S*0.1803..) -> bf16 -> Ps LDS [q][key] stride 72 (wave-private)
//   O += P·V_ext, V_ext = Vt rows 0..63 = V^T[d][key], row 64 = ones (gives l)
//   epilogue: O[q][d] = Oacc/l.
// ---------------------------------------------------------------------------
#define PS_STRIDE 72
__global__ __launch_bounds__(256) void flash_mfma_kernel(
    const short* __restrict__ Q, const short* __restrict__ K,
    const short* __restrict__ Vt, short* __restrict__ O)
{
  __shared__ short Ks[64 * 64];        // [key][d]
  __shared__ short Vts[80 * 64];       // [d][key]; rows 64..79: ones / zeros
  __shared__ short Ps[64 * PS_STRIDE]; // [q][key], wave-private 16-row strips

  const int tid = threadIdx.x;
  const int wave = tid >> 6, lane = tid & 63;
  const int quad = lane >> 4, r16 = lane & 15;
  const int qb = blockIdx.x, h = blockIdx.y, b = blockIdx.z;
  const int q0 = qb * 64, wq = wave * 16;

  const size_t kbase = ((size_t)b * 2048) * 1024 + (size_t)h * 64;  // + key*1024 + d
  const size_t vbase = ((size_t)h * 64) * 4096 + (size_t)b * 2048;  // + d*4096 + key

  // init V_ext tail rows (64 = ones, 65..79 = zero); persists across K-tiles
  {
    const int idx = 64 * 64 + tid * 4;
    const short val = (idx < 65 * 64) ? (short)0x3F80 : (short)0;
    bf16x4 v4 = {val, val, val, val};
    *(bf16x4*)(&Vts[idx]) = v4;
  }

  // Q A-fragments in registers: lane holds Q[q0+wq+r16][kk*32+quad*8 .. +7]
  bf16x8 qf[2];
  {
    const size_t qrow = ((size_t)b * 2048 + q0 + wq + r16) * 1024 + (size_t)h * 64;
    qf[0] = *(const bf16x8*)(Q + qrow + quad * 8);
    qf[1] = *(const bf16x8*)(Q + qrow + 32 + quad * 8);
  }

  f32x4 oacc[5];
#pragma unroll
  for (int n = 0; n < 5; n++) oacc[n] = (f32x4){0.f, 0.f, 0.f, 0.f};

  // staging source: lane covers row (wq + (lane>>3) [+8]) , col (lane&7)*8
  const int srow = lane >> 3, sc8 = (lane & 7) * 8;

  for (int kt = 0; kt < 32; kt++){
    const short* ksrc = K + kbase + (size_t)(kt * 64 + wq + srow) * 1024 + sc8;
    const short* vsrc = Vt + vbase + (size_t)(wq + srow) * 4096 + kt * 64 + sc8;
    gl_lds16(ksrc,            &Ks[wq * 64]);
    gl_lds16(ksrc + 8 * 1024, &Ks[wq * 64 + 512]);
    gl_lds16(vsrc,            &Vts[wq * 64]);
    gl_lds16(vsrc + 8 * 4096, &Vts[wq * 64 + 512]);
    __syncthreads();

    // ---- S = Q·K^T over 4 key tiles ----
    f32x4 sacc[4];
#pragma unroll
    for (int nt = 0; nt < 4; nt++){
      bf16x8 kf0 = *(const bf16x8*)(&Ks[(nt * 16 + r16) * 64 + quad * 8]);
      bf16x8 kf1 = *(const bf16x8*)(&Ks[(nt * 16 + r16) * 64 + 32 + quad * 8]);
      f32x4 s = (f32x4){0.f, 0.f, 0.f, 0.f};
      s = __builtin_amdgcn_mfma_f32_16x16x32_bf16(qf[0], kf0, s, 0, 0, 0);
      s = __builtin_amdgcn_mfma_f32_16x16x32_bf16(qf[1], kf1, s, 0, 0, 0);
      sacc[nt] = s;
    }

    // ---- P = exp(S*0.125) in bf16 -> Ps (wave-private rows) ----
#pragma unroll
    for (int nt = 0; nt < 4; nt++)
#pragma unroll
      for (int t = 0; t < 4; t++)
        Ps[(wq + quad * 4 + t) * PS_STRIDE + nt * 16 + r16] =
            f2b(__builtin_amdgcn_exp2f(sacc[nt][t] * 0.18033688f));

    // ---- O += P·V_ext ----
#pragma unroll
    for (int kk = 0; kk < 2; kk++){
      bf16x8 pf = *(const bf16x8*)(&Ps[(wq + r16) * PS_STRIDE + kk * 32 + quad * 8]);
#pragma unroll
      for (int nt = 0; nt < 5; nt++){
        bf16x8 vf = *(const bf16x8*)(&Vts[(nt * 16 + r16) * 64 + kk * 32 + quad * 8]);
        oacc[nt] = __builtin_amdgcn_mfma_f32_16x16x32_bf16(pf, vf, oacc[nt], 0, 0, 0);
      }
    }
    __syncthreads();
  }

  // ---- epilogue: O = Oacc / l ; l sits in oacc[4][t] at r16==0 of each quad
  float linv[4];
#pragma unroll
  for (int t = 0; t < 4; t++){
    const float l = __shfl(oacc[4][t], lane & 48, 64);
    linv[t] = 1.0f / l;
  }
  const size_t obase = ((size_t)b * 2048 + q0 + wq) * 1024 + (size_t)h * 64;
#pragma unroll
  for (int nt = 0; nt < 4; nt++)
#pragma unroll
    for (int t = 0; t < 4; t++)
      O[obase + (size_t)(quad * 4 + t) * 1024 + nt * 16 + r16] =
          f2b(oacc[nt][t] * linv[t]);
}

// ---------------------------------------------------------------------------
extern "C" void kernel_launch(void* const* d_in, const int* in_sizes, int n_in,
                              void* d_out, int out_size, void* d_ws, size_t ws_size,
                              hipStream_t stream) {
  const float* emb  = (const float*)d_in[0];
  const float* ctx  = (const float*)d_in[1];
  const float* Wq   = (const float*)d_in[2];
  const float* Wk   = (const float*)d_in[3];
  const float* Wv   = (const float*)d_in[4];
  const float* Wu   = (const float*)d_in[5];
  const float* bu   = (const float*)d_in[6];
  const float* qn_w = (const float*)d_in[7];
  const float* qn_b = (const float*)d_in[8];
  const float* kn_w = (const float*)d_in[9];
  const float* kn_b = (const float*)d_in[10];
  float* out = (float*)d_out;

  const size_t BIG = (size_t)4096 * 1024;   // 4M elems
  const size_t WSZ = (size_t)1024 * 1024;   // 1M elems
  short* ws   = (short*)d_ws;
  short* embh = ws;
  short* ctxh = embh + BIG;
  short* Wqh  = ctxh + BIG;
  short* Wkh  = Wqh + WSZ;
  short* Wvh  = Wkh + WSZ;
  short* Wuh  = Wvh + WSZ;
  short* qh   = Wuh + WSZ;
  short* kh   = qh + BIG;
  short* vth  = kh + BIG;    // V^T: [inner 1024][token 4096]
  short* aoh  = vth + BIG;

  cvt_kernel<<<4096, 256, 0, stream>>>(emb, embh, (int)BIG);
  cvt_kernel<<<4096, 256, 0, stream>>>(ctx, ctxh, (int)BIG);
  cvt_kernel<<<1024, 256, 0, stream>>>(Wq, Wqh, (int)WSZ);
  cvt_kernel<<<1024, 256, 0, stream>>>(Wk, Wkh, (int)WSZ);
  cvt_kernel<<<1024, 256, 0, stream>>>(Wv, Wvh, (int)WSZ);
  cvt_kernel<<<1024, 256, 0, stream>>>(Wu, Wuh, (int)WSZ);

  dim3 gg(8, 32);    // (N/128, M/128)
  gemm_bt_kernel<<<gg, 256, 0, stream>>>(embh, Wqh, qh, nullptr, nullptr, 1024, 0);
  gemm_bt_kernel<<<gg, 256, 0, stream>>>(ctxh, Wkh, kh, nullptr, nullptr, 1024, 0);
  dim3 gv(32, 8);    // V^T = Wv @ ctx^T : M=1024, N=4096
  gemm_bt_kernel<<<gv, 256, 0, stream>>>(Wvh, ctxh, vth, nullptr, nullptr, 4096, 0);

  ln_kernel<<<16384, 256, 0, stream>>>(qh, qn_w, qn_b);
  ln_kernel<<<16384, 256, 0, stream>>>(kh, kn_w, kn_b);

  dim3 ga(32, 16, 2);   // qblock, head, batch
  flash_mfma_kernel<<<ga, 256, 0, stream>>>(qh, kh, vth, aoh);

  gemm_bt_kernel<<<gg, 256, 0, stream>>>(aoh, Wuh, nullptr, out, bu, 1024, 1);
}

// Round 3
// 238.751 us; speedup vs baseline: 4.4686x; 1.4139x over previous
//
#include <hip/hip_runtime.h>

// ============================================================================
// MultiHeadCrossAttention on MI355X (gfx950) — round 3
//   B=2, SQ=SK=2048, H=16, D=64, EMB=CTX=INNER=1024, fp32 in/out.
//
// 5 dispatches:
//   1. cvt6: all fp32->bf16 conversions in one kernel
//   2. gemm<0> (z=2): q = emb@Wq^T, k = ctx@Wk^T, LN fused in epilogue
//   3. gemm<1>: vT = Wv@ctx^T with key-permuted columns (PV frag order)
//   4. flash2: S^T = K·Q^T (32x32x16 MFMA) -> P in registers -> O^T = V^T·P^T
//      (zero LDS for P; XOR-swizzled K/V staging; double-buffered gl_lds)
//   5. gemm<2>: out = ao@Wu^T + bu (fp32)
// ============================================================================

typedef __attribute__((ext_vector_type(8)))  short bf16x8;
typedef __attribute__((ext_vector_type(4)))  short bf16x4;
typedef __attribute__((ext_vector_type(4)))  float f32x4;
typedef __attribute__((ext_vector_type(16))) float f32x16;

typedef __attribute__((address_space(1))) const void cg_void;
typedef __attribute__((address_space(3))) void lds_void_t;

__device__ __forceinline__ void gl_lds16(const void* g, void* l){
  __builtin_amdgcn_global_load_lds((cg_void*)g, (lds_void_t*)l, 16, 0, 0);
}

__device__ __forceinline__ float b2f(short h){
  unsigned int u = ((unsigned int)(unsigned short)h) << 16;
  float f;
  __builtin_memcpy(&f, &u, 4);
  return f;
}
__device__ __forceinline__ short f2b(float f){
  unsigned int u;
  __builtin_memcpy(&u, &f, 4);
  u += 0x7fffu + ((u >> 16) & 1u);   // round-to-nearest-even
  return (short)(u >> 16);
}

// ---------------------------------------------------------------------------
// Fused fp32 -> bf16 convert of all six inputs (12M elems, 4 per thread).
// Regions: emb[0,4M) ctx[4M,8M) Wq[8M,9M) Wk[9M,10M) Wv[10M,11M) Wu[11M,12M)
// ---------------------------------------------------------------------------
__global__ __launch_bounds__(256) void cvt6_kernel(
    const float* __restrict__ emb, const float* __restrict__ ctx,
    const float* __restrict__ Wq, const float* __restrict__ Wk,
    const float* __restrict__ Wv, const float* __restrict__ Wu,
    short* __restrict__ o_emb, short* __restrict__ o_ctx,
    short* __restrict__ o_wq, short* __restrict__ o_wk,
    short* __restrict__ o_wv, short* __restrict__ o_wu)
{
  const long M1 = 1024L * 1024L, M4 = 4L * M1;
  long e = ((long)blockIdx.x * 256 + threadIdx.x) * 4;
  if (e >= 12L * M1) return;
  const float* src; short* dst; long off;
  if      (e <     M4)      { src = emb; dst = o_emb; off = e;           }
  else if (e < 2 * M4)      { src = ctx; dst = o_ctx; off = e - M4;      }
  else if (e < 2 * M4 + M1) { src = Wq;  dst = o_wq;  off = e - 2 * M4;  }
  else if (e < 2 * M4 + 2*M1){src = Wk;  dst = o_wk;  off = e - 2*M4 - M1;}
  else if (e < 2 * M4 + 3*M1){src = Wv;  dst = o_wv;  off = e - 2*M4 - 2*M1;}
  else                      { src = Wu;  dst = o_wu;  off = e - 2*M4 - 3*M1;}
  f32x4 v = *(const f32x4*)(src + off);
  bf16x4 o;
  o[0] = f2b(v[0]); o[1] = f2b(v[1]); o[2] = f2b(v[2]); o[3] = f2b(v[3]);
  *(bf16x4*)(dst + off) = o;
}

// ---------------------------------------------------------------------------
// C[M,N] = A[M,K] @ B[N,K]^T, bf16 in, fp32 accum. K=1024. 128x128 tile,
// 4 waves 2x2, wave 64x64 (4x4 MFMA 16x16x32). m97-style gl_lds staging.
// MODE 0: blockIdx.z selects (A0,B0,ln0,Ch0)/(A1,B1,ln1,Ch1); LN over the
//         64-col head chunk fused in the epilogue; bf16 out.
// MODE 1: bf16 out with key-permuted columns (PV B-frag order), N=4096.
// MODE 2: fp32 out + bias[col].
// ---------------------------------------------------------------------------
template<int MODE>
__global__ __launch_bounds__(256) void gemm_kernel(
    const short* __restrict__ A0, const short* __restrict__ B0,
    const short* __restrict__ A1, const short* __restrict__ B1,
    short* __restrict__ Ch0, short* __restrict__ Ch1,
    float* __restrict__ Cf,
    const float* __restrict__ w0, const float* __restrict__ bw0,
    const float* __restrict__ w1, const float* __restrict__ bw1,
    const float* __restrict__ bias, int N)
{
  const int K = 1024;
  __shared__ short As[128 * 64];
  __shared__ short Bs[128 * 64];
  const int tid  = threadIdx.x;
  const int wave = tid >> 6, lane = tid & 63;
  const int quad = lane >> 4, r16 = lane & 15;
  const int wm = (wave >> 1) * 64, wn = (wave & 1) * 64;
  const int bm = blockIdx.y * 128, bn = blockIdx.x * 128;

  const short* A = A0; const short* B = B0;
  short* Ch = Ch0;
  const float* lw = w0; const float* lb = bw0;
  if (MODE == 0 && blockIdx.z == 1){ A = A1; B = B1; Ch = Ch1; lw = w1; lb = bw1; }

  f32x4 acc[4][4];
#pragma unroll
  for (int i = 0; i < 4; i++)
#pragma unroll
    for (int j = 0; j < 4; j++)
      acc[i][j] = (f32x4){0.f, 0.f, 0.f, 0.f};

  const size_t arow = (size_t)(bm + wave * 8 + (lane >> 3)) * K + (lane & 7) * 8;
  const size_t brow = (size_t)(bn + wave * 8 + (lane >> 3)) * K + (lane & 7) * 8;

  for (int k0 = 0; k0 < K; k0 += 64){
#pragma unroll
    for (int i = 0; i < 4; i++){
      gl_lds16(A + arow + (size_t)32 * i * K + k0, &As[wave * 512 + i * 2048]);
      gl_lds16(B + brow + (size_t)32 * i * K + k0, &Bs[wave * 512 + i * 2048]);
    }
    __syncthreads();
#pragma unroll
    for (int kk = 0; kk < 2; kk++){
      bf16x8 af[4], bq[4];
#pragma unroll
      for (int i = 0; i < 4; i++)
        af[i] = *(const bf16x8*)(&As[(wm + i*16 + r16) * 64 + kk*32 + quad*8]);
#pragma unroll
      for (int j = 0; j < 4; j++)
        bq[j] = *(const bf16x8*)(&Bs[(wn + j*16 + r16) * 64 + kk*32 + quad*8]);
#pragma unroll
      for (int i = 0; i < 4; i++)
#pragma unroll
        for (int j = 0; j < 4; j++)
          acc[i][j] = __builtin_amdgcn_mfma_f32_16x16x32_bf16(af[i], bq[j], acc[i][j], 0, 0, 0);
    }
    __syncthreads();
  }

  if (MODE == 0){
    // LN over the wave's 64 cols (one head chunk). dim = j*16 + r16.
    float wv[4], bv[4];
#pragma unroll
    for (int j = 0; j < 4; j++){ wv[j] = lw[j*16 + r16]; bv[j] = lb[j*16 + r16]; }
#pragma unroll
    for (int i = 0; i < 4; i++){
#pragma unroll
      for (int t = 0; t < 4; t++){
        float a[4];
#pragma unroll
        for (int j = 0; j < 4; j++) a[j] = acc[i][j][t];
        float s = a[0] + a[1] + a[2] + a[3];
        s += __shfl_xor(s, 1); s += __shfl_xor(s, 2);
        s += __shfl_xor(s, 4); s += __shfl_xor(s, 8);
        const float mu = s * 0.015625f;
        float d[4], sq = 0.f;
#pragma unroll
        for (int j = 0; j < 4; j++){ d[j] = a[j] - mu; sq += d[j]*d[j]; }
        sq += __shfl_xor(sq, 1); sq += __shfl_xor(sq, 2);
        sq += __shfl_xor(sq, 4); sq += __shfl_xor(sq, 8);
        const float si = rsqrtf(sq * 0.015625f + 1e-5f);
        const size_t row = (size_t)(bm + wm + i*16 + quad*4 + t);
#pragma unroll
        for (int j = 0; j < 4; j++)
          Ch[row * N + (bn + wn + j*16 + r16)] = f2b(d[j] * si * wv[j] + bv[j]);
      }
    }
  } else {
#pragma unroll
    for (int i = 0; i < 4; i++){
#pragma unroll
      for (int j = 0; j < 4; j++){
        int col = bn + wn + j*16 + r16;
        if (MODE == 1){
          // permute token index within its 32-group into PV fragment order
          const int p = (r16 & 3) | ((j & 1) << 2) | (((r16 >> 2) & 1) << 3)
                        | (((r16 >> 3) & 1) << 4);
          col = (col & ~31) | p;
        }
#pragma unroll
        for (int t = 0; t < 4; t++){
          const size_t row = (size_t)(bm + wm + i*16 + quad*4 + t);
          const float v = acc[i][j][t];
          if (MODE == 1) Ch[row * (size_t)N + col] = f2b(v);
          else           Cf[row * (size_t)N + col] = v + bias[col];
        }
      }
    }
  }
}

// ---------------------------------------------------------------------------
// MFMA flash attention v2 — 32x32x16, S^T trick, P in registers.
//   Grid (16 qb, 16 h, 2 b), 256 threads = 4 waves x 32 queries = 128 q/block.
//   Per 64-key staged tile (Ks [key][d], Vts [d][key_perm], both XOR-swizzled):
//     S^T = K·Q^T  -> C-layout: lane holds col=q(=lane&31), 16 key-rows
//     P = exp2(S^T * 0.125*log2e) -> regs -> directly the B-frag of
//     O^T = V^T·P^T (key order baked into Vt's global column permutation).
//   l = per-lane fp32 sum + shfl_xor(32). No running max (LN bounds |S|<=64).
// ---------------------------------------------------------------------------
__global__ __launch_bounds__(256) void flash2_kernel(
    const short* __restrict__ Q, const short* __restrict__ K,
    const short* __restrict__ Vt, short* __restrict__ O)
{
  __shared__ short Ks[2][64 * 64];   // [key][d], chunk ^= key&7
  __shared__ short Vts[2][64 * 64];  // [d][key], chunk ^= d&7

  const int tid = threadIdx.x;
  const int wave = tid >> 6, lane = tid & 63;
  const int hh = lane >> 5, q5 = lane & 31;
  const int qb = blockIdx.x, h = blockIdx.y, b = blockIdx.z;
  const int q0 = qb * 128 + wave * 32;

  const size_t kbase = ((size_t)b * 2048) * 1024 + (size_t)h * 64;
  const size_t vbase = ((size_t)h * 64) * 4096 + (size_t)b * 2048;

  // Q B-frags: lane holds Q[q0+q5][c*16 + hh*8 + j]
  bf16x8 qf[4];
  {
    const size_t qrow = ((size_t)b * 2048 + q0 + q5) * 1024 + (size_t)h * 64;
#pragma unroll
    for (int c = 0; c < 4; c++)
      qf[c] = *(const bf16x8*)(Q + qrow + c * 16 + hh * 8);
  }

  f32x16 oacc[2];
#pragma unroll
  for (int mt = 0; mt < 2; mt++)
#pragma unroll
    for (int t = 0; t < 16; t++) oacc[mt][t] = 0.f;
  float lsum = 0.f;

  // staging: wave stages rows [wave*16, wave*16+16); source chunk XOR-swizzled
  const int srow = lane >> 3;
  const int csrc = ((lane & 7) ^ srow) * 8;   // shorts
  const int wr0 = wave * 16;

#define STAGE(bufi, kt)                                                        \
  {                                                                            \
    const short* ks = K + kbase + (size_t)((kt) * 64 + wr0 + srow) * 1024 + csrc; \
    const short* vs = Vt + vbase + (size_t)(wr0 + srow) * 4096 + (kt) * 64 + csrc; \
    gl_lds16(ks,            &Ks[bufi][wr0 * 64]);                              \
    gl_lds16(ks + 8 * 1024, &Ks[bufi][(wr0 + 8) * 64]);                        \
    gl_lds16(vs,            &Vts[bufi][wr0 * 64]);                             \
    gl_lds16(vs + 8 * 4096, &Vts[bufi][(wr0 + 8) * 64]);                       \
  }

  STAGE(0, 0)

  for (int kt = 0; kt < 32; kt++){
    const int buf = kt & 1;
    __syncthreads();                        // staging(buf) done, buf^1 free
    if (kt + 1 < 32) STAGE(buf ^ 1, kt + 1)

#pragma unroll
    for (int s32 = 0; s32 < 2; s32++){
      // ---- S^T = K·Q^T ----
      f32x16 sacc;
#pragma unroll
      for (int t = 0; t < 16; t++) sacc[t] = 0.f;
      const int key = s32 * 32 + q5;
#pragma unroll
      for (int c = 0; c < 4; c++){
        bf16x8 kf = *(const bf16x8*)(&Ks[buf][key * 64 + (((2*c + hh) ^ (key & 7)) << 3)]);
        sacc = __builtin_amdgcn_mfma_f32_32x32x16_bf16(kf, qf[c], sacc, 0, 0, 0);
      }

      // ---- P = exp2(S^T * scale) in regs; l accumulates in fp32 ----
      short pb[16];
#pragma unroll
      for (int t = 0; t < 16; t++){
        const float p = __builtin_amdgcn_exp2f(sacc[t] * 0.18033688f);
        lsum += p;
        pb[t] = f2b(p);
      }

      // ---- O^T += V^T·P^T ----
#pragma unroll
      for (int c = 0; c < 2; c++){
        bf16x8 pf;
#pragma unroll
        for (int j = 0; j < 8; j++) pf[j] = pb[(j & 3) + 4*c + 8*(j >> 2)];
#pragma unroll
        for (int mt = 0; mt < 2; mt++){
          const int d = mt * 32 + q5;
          bf16x8 vf = *(const bf16x8*)(&Vts[buf][d * 64 + (((s32*4 + 2*c + hh) ^ (d & 7)) << 3)]);
          oacc[mt] = __builtin_amdgcn_mfma_f32_32x32x16_bf16(vf, pf, oacc[mt], 0, 0, 0);
        }
      }
    }
  }

  // ---- epilogue: O[q][d] = O^T / l ----
  lsum += __shfl_xor(lsum, 32);
  const float linv = 1.0f / lsum;
  const size_t orow = ((size_t)b * 2048 + q0 + q5) * 1024 + (size_t)h * 64;
#pragma unroll
  for (int mt = 0; mt < 2; mt++){
#pragma unroll
    for (int g = 0; g < 4; g++){
      bf16x4 o4;
#pragma unroll
      for (int u = 0; u < 4; u++) o4[u] = f2b(oacc[mt][g*4 + u] * linv);
      *(bf16x4*)(O + orow + mt*32 + g*8 + 4*hh) = o4;   // d = u + 8g + 4hh + 32mt
    }
  }
}

// ---------------------------------------------------------------------------
extern "C" void kernel_launch(void* const* d_in, const int* in_sizes, int n_in,
                              void* d_out, int out_size, void* d_ws, size_t ws_size,
                              hipStream_t stream) {
  const float* emb  = (const float*)d_in[0];
  const float* ctx  = (const float*)d_in[1];
  const float* Wq   = (const float*)d_in[2];
  const float* Wk   = (const float*)d_in[3];
  const float* Wv   = (const float*)d_in[4];
  const float* Wu   = (const float*)d_in[5];
  const float* bu   = (const float*)d_in[6];
  const float* qn_w = (const float*)d_in[7];
  const float* qn_b = (const float*)d_in[8];
  const float* kn_w = (const float*)d_in[9];
  const float* kn_b = (const float*)d_in[10];
  float* out = (float*)d_out;

  const size_t BIG = (size_t)4096 * 1024;
  const size_t WSZ = (size_t)1024 * 1024;
  short* ws   = (short*)d_ws;
  short* embh = ws;
  short* ctxh = embh + BIG;
  short* Wqh  = ctxh + BIG;
  short* Wkh  = Wqh + WSZ;
  short* Wvh  = Wkh + WSZ;
  short* Wuh  = Wvh + WSZ;
  short* qh   = Wuh + WSZ;
  short* kh   = qh + BIG;
  short* vth  = kh + BIG;    // V^T [inner][token], key-permuted columns
  short* aoh  = vth + BIG;

  cvt6_kernel<<<12288, 256, 0, stream>>>(emb, ctx, Wq, Wk, Wv, Wu,
                                         embh, ctxh, Wqh, Wkh, Wvh, Wuh);

  // q & k projections + fused LN, one dispatch (z picks stream)
  gemm_kernel<0><<<dim3(8, 32, 2), 256, 0, stream>>>(
      embh, Wqh, ctxh, Wkh, qh, kh, nullptr,
      qn_w, qn_b, kn_w, kn_b, nullptr, 1024);

  // vT = Wv @ ctx^T with permuted token columns
  gemm_kernel<1><<<dim3(32, 8, 1), 256, 0, stream>>>(
      Wvh, ctxh, nullptr, nullptr, vth, nullptr, nullptr,
      nullptr, nullptr, nullptr, nullptr, nullptr, 4096);

  flash2_kernel<<<dim3(16, 16, 2), 256, 0, stream>>>(qh, kh, vth, aoh);

  gemm_kernel<2><<<dim3(8, 32, 1), 256, 0, stream>>>(
      aoh, Wuh, nullptr, nullptr, nullptr, nullptr, out,
      nullptr, nullptr, nullptr, nullptr, bu, 1024);
}

// Round 4
// 231.867 us; speedup vs baseline: 4.6013x; 1.0297x over previous
//
#include <hip/hip_runtime.h>

// ============================================================================
// MultiHeadCrossAttention on MI355X (gfx950) — round 4
//   B=2, SQ=SK=2048, H=16, D=64, EMB=CTX=INNER=1024, fp32 in/out.
//
// 4 dispatches:
//   1. cvt6: all fp32->bf16 conversions
//   2. gemm_qkv (768 blocks, 3 tasks): q=emb@Wq^T+LN, k=ctx@Wk^T+LN,
//      vT=Wv@ctx^T (key-permuted cols)  — fused for occupancy (3 blocks/CU)
//   3. flash2: 8-wave blocks, 2-way K-split (4 waves/SIMD), S^T=K·Q^T
//      (32x32x16), P packed in-register via v_perm, O^T=V^T·P^T, LDS combine
//   4. gemm_out: out = ao@Wu^T + bu, BK=128
// ============================================================================

typedef __attribute__((ext_vector_type(8)))  short bf16x8;
typedef __attribute__((ext_vector_type(4)))  short bf16x4;
typedef __attribute__((ext_vector_type(4)))  float f32x4;
typedef __attribute__((ext_vector_type(16))) float f32x16;
typedef __attribute__((ext_vector_type(4)))  unsigned int u32x4;

typedef __attribute__((address_space(1))) const void cg_void;
typedef __attribute__((address_space(3))) void lds_void_t;

__device__ __forceinline__ void gl_lds16(const void* g, void* l){
  __builtin_amdgcn_global_load_lds((cg_void*)g, (lds_void_t*)l, 16, 0, 0);
}

__device__ __forceinline__ short f2b(float f){
  unsigned int u;
  __builtin_memcpy(&u, &f, 4);
  u += 0x7fffu + ((u >> 16) & 1u);   // round-to-nearest-even
  return (short)(u >> 16);
}

// ---------------------------------------------------------------------------
// Fused fp32 -> bf16 convert of all six inputs (12M elems, 4 per thread).
// ---------------------------------------------------------------------------
__global__ __launch_bounds__(256) void cvt6_kernel(
    const float* __restrict__ emb, const float* __restrict__ ctx,
    const float* __restrict__ Wq, const float* __restrict__ Wk,
    const float* __restrict__ Wv, const float* __restrict__ Wu,
    short* __restrict__ o_emb, short* __restrict__ o_ctx,
    short* __restrict__ o_wq, short* __restrict__ o_wk,
    short* __restrict__ o_wv, short* __restrict__ o_wu)
{
  const long M1 = 1024L * 1024L, M4 = 4L * M1;
  long e = ((long)blockIdx.x * 256 + threadIdx.x) * 4;
  if (e >= 12L * M1) return;
  const float* src; short* dst; long off;
  if      (e <     M4)      { src = emb; dst = o_emb; off = e;           }
  else if (e < 2 * M4)      { src = ctx; dst = o_ctx; off = e - M4;      }
  else if (e < 2 * M4 + M1) { src = Wq;  dst = o_wq;  off = e - 2 * M4;  }
  else if (e < 2 * M4 + 2*M1){src = Wk;  dst = o_wk;  off = e - 2*M4 - M1;}
  else if (e < 2 * M4 + 3*M1){src = Wv;  dst = o_wv;  off = e - 2*M4 - 2*M1;}
  else                      { src = Wu;  dst = o_wu;  off = e - 2*M4 - 3*M1;}
  f32x4 v = *(const f32x4*)(src + off);
  bf16x4 o;
  o[0] = f2b(v[0]); o[1] = f2b(v[1]); o[2] = f2b(v[2]); o[3] = f2b(v[3]);
  *(bf16x4*)(dst + off) = o;
}

// ---------------------------------------------------------------------------
// Fused QKV projections. Grid (256, 3); blockIdx.y = task.
//   task 0: q = emb@Wq^T + LN   (bn = x&7,  bm = x>>3;  N=1024)
//   task 1: k = ctx@Wk^T + LN   (same tiling)
//   task 2: vT = Wv@ctx^T, key-permuted columns (bn = x&31, bm = x>>5; N=4096)
// 128x128 tile, BK=64, 4 waves 2x2, MFMA 16x16x32, gl_lds staging (m97).
// ---------------------------------------------------------------------------
__global__ __launch_bounds__(256) void gemm_qkv_kernel(
    const short* __restrict__ embh, const short* __restrict__ ctxh,
    const short* __restrict__ Wqh, const short* __restrict__ Wkh,
    const short* __restrict__ Wvh,
    short* __restrict__ qo, short* __restrict__ ko, short* __restrict__ vto,
    const float* __restrict__ qw, const float* __restrict__ qb,
    const float* __restrict__ kw, const float* __restrict__ kb)
{
  const int K = 1024;
  __shared__ short As[128 * 64];
  __shared__ short Bs[128 * 64];
  const int tid  = threadIdx.x;
  const int wave = tid >> 6, lane = tid & 63;
  const int quad = lane >> 4, r16 = lane & 15;
  const int wm = (wave >> 1) * 64, wn = (wave & 1) * 64;

  const int task = blockIdx.y;
  int bn, bm, N;
  const short *A, *B;
  if (task == 2){
    bn = (blockIdx.x & 31) * 128; bm = (blockIdx.x >> 5) * 128; N = 4096;
    A = Wvh; B = ctxh;
  } else {
    bn = (blockIdx.x & 7) * 128; bm = (blockIdx.x >> 3) * 128; N = 1024;
    A = task ? ctxh : embh; B = task ? Wkh : Wqh;
  }

  f32x4 acc[4][4];
#pragma unroll
  for (int i = 0; i < 4; i++)
#pragma unroll
    for (int j = 0; j < 4; j++)
      acc[i][j] = (f32x4){0.f, 0.f, 0.f, 0.f};

  const size_t arow = (size_t)(bm + wave * 8 + (lane >> 3)) * K + (lane & 7) * 8;
  const size_t brow = (size_t)(bn + wave * 8 + (lane >> 3)) * K + (lane & 7) * 8;

  for (int k0 = 0; k0 < K; k0 += 64){
#pragma unroll
    for (int i = 0; i < 4; i++){
      gl_lds16(A + arow + (size_t)32 * i * K + k0, &As[wave * 512 + i * 2048]);
      gl_lds16(B + brow + (size_t)32 * i * K + k0, &Bs[wave * 512 + i * 2048]);
    }
    __syncthreads();
#pragma unroll
    for (int kk = 0; kk < 2; kk++){
      bf16x8 af[4], bq[4];
#pragma unroll
      for (int i = 0; i < 4; i++)
        af[i] = *(const bf16x8*)(&As[(wm + i*16 + r16) * 64 + kk*32 + quad*8]);
#pragma unroll
      for (int j = 0; j < 4; j++)
        bq[j] = *(const bf16x8*)(&Bs[(wn + j*16 + r16) * 64 + kk*32 + quad*8]);
#pragma unroll
      for (int i = 0; i < 4; i++)
#pragma unroll
        for (int j = 0; j < 4; j++)
          acc[i][j] = __builtin_amdgcn_mfma_f32_16x16x32_bf16(af[i], bq[j], acc[i][j], 0, 0, 0);
    }
    __syncthreads();
  }

  if (task < 2){
    short* Ch = task ? ko : qo;
    const float* lw = task ? kw : qw;
    const float* lb = task ? kb : qb;
    float wv[4], bv[4];
#pragma unroll
    for (int j = 0; j < 4; j++){ wv[j] = lw[j*16 + r16]; bv[j] = lb[j*16 + r16]; }
#pragma unroll
    for (int i = 0; i < 4; i++){
#pragma unroll
      for (int t = 0; t < 4; t++){
        float a[4];
#pragma unroll
        for (int j = 0; j < 4; j++) a[j] = acc[i][j][t];
        float s = a[0] + a[1] + a[2] + a[3];
        s += __shfl_xor(s, 1); s += __shfl_xor(s, 2);
        s += __shfl_xor(s, 4); s += __shfl_xor(s, 8);
        const float mu = s * 0.015625f;
        float d[4], sq = 0.f;
#pragma unroll
        for (int j = 0; j < 4; j++){ d[j] = a[j] - mu; sq += d[j]*d[j]; }
        sq += __shfl_xor(sq, 1); sq += __shfl_xor(sq, 2);
        sq += __shfl_xor(sq, 4); sq += __shfl_xor(sq, 8);
        const float si = rsqrtf(sq * 0.015625f + 1e-5f);
        const size_t row = (size_t)(bm + wm + i*16 + quad*4 + t);
#pragma unroll
        for (int j = 0; j < 4; j++)
          Ch[row * 1024 + (bn + wn + j*16 + r16)] = f2b(d[j] * si * wv[j] + bv[j]);
      }
    }
  } else {
#pragma unroll
    for (int i = 0; i < 4; i++){
#pragma unroll
      for (int j = 0; j < 4; j++){
        // permute token index within its 32-group into PV fragment order
        const int p = (r16 & 3) | ((j & 1) << 2) | (((r16 >> 2) & 1) << 3)
                      | (((r16 >> 3) & 1) << 4);
        const int col = ((bn + wn + j*16 + r16) & ~31) | p;
#pragma unroll
        for (int t = 0; t < 4; t++){
          const size_t row = (size_t)(bm + wm + i*16 + quad*4 + t);
          vto[row * (size_t)N + col] = f2b(acc[i][j][t]);
        }
      }
    }
  }
}

// ---------------------------------------------------------------------------
// out = ao @ Wu^T + bu. M=4096, N=K=1024, fp32 out. 128x128 tile, BK=128
// (8 barriers; grid-limited 2 blocks/CU so the 64KB LDS costs nothing).
// ---------------------------------------------------------------------------
__global__ __launch_bounds__(256) void gemm_out_kernel(
    const short* __restrict__ A, const short* __restrict__ B,
    float* __restrict__ Cf, const float* __restrict__ bias)
{
  const int K = 1024, N = 1024;
  __shared__ short As[128 * 128];
  __shared__ short Bs[128 * 128];
  const int tid  = threadIdx.x;
  const int wave = tid >> 6, lane = tid & 63;
  const int quad = lane >> 4, r16 = lane & 15;
  const int wm = (wave >> 1) * 64, wn = (wave & 1) * 64;
  const int bm = blockIdx.y * 128, bn = blockIdx.x * 128;

  f32x4 acc[4][4];
#pragma unroll
  for (int i = 0; i < 4; i++)
#pragma unroll
    for (int j = 0; j < 4; j++)
      acc[i][j] = (f32x4){0.f, 0.f, 0.f, 0.f};

  // staging: lane covers row (lane>>4), 16B-chunk (lane&15); 4 rows/instr
  const size_t arow = (size_t)(bm + wave * 4 + (lane >> 4)) * K + (lane & 15) * 8;
  const size_t brow = (size_t)(bn + wave * 4 + (lane >> 4)) * K + (lane & 15) * 8;

  for (int k0 = 0; k0 < K; k0 += 128){
#pragma unroll
    for (int i = 0; i < 8; i++){
      gl_lds16(A + arow + (size_t)16 * i * K + k0, &As[(wave * 4 + i * 16) * 128]);
      gl_lds16(B + brow + (size_t)16 * i * K + k0, &Bs[(wave * 4 + i * 16) * 128]);
    }
    __syncthreads();
#pragma unroll
    for (int kk = 0; kk < 4; kk++){
      bf16x8 af[4], bq[4];
#pragma unroll
      for (int i = 0; i < 4; i++)
        af[i] = *(const bf16x8*)(&As[(wm + i*16 + r16) * 128 + kk*32 + quad*8]);
#pragma unroll
      for (int j = 0; j < 4; j++)
        bq[j] = *(const bf16x8*)(&Bs[(wn + j*16 + r16) * 128 + kk*32 + quad*8]);
#pragma unroll
      for (int i = 0; i < 4; i++)
#pragma unroll
        for (int j = 0; j < 4; j++)
          acc[i][j] = __builtin_amdgcn_mfma_f32_16x16x32_bf16(af[i], bq[j], acc[i][j], 0, 0, 0);
    }
    __syncthreads();
  }

#pragma unroll
  for (int i = 0; i < 4; i++){
#pragma unroll
    for (int j = 0; j < 4; j++){
      const int col = bn + wn + j*16 + r16;
#pragma unroll
      for (int t = 0; t < 4; t++){
        const size_t row = (size_t)(bm + wm + i*16 + quad*4 + t);
        Cf[row * N + col] = acc[i][j][t] + bias[col];
      }
    }
  }
}

// ---------------------------------------------------------------------------
// MFMA flash attention v3 — 8 waves, 2-way K-split.
//   Grid (16 qb, 16 h, 2 b), 512 threads. Block covers 128 queries.
//   wave = half*4 + wg: wg = query group (32 q), half = K-parity (even/odd kt).
//   Per half: double-buffered 64-key tiles (Ks [key][d], Vts [d][key_perm],
//   XOR-swizzled). S^T = K·Q^T (32x32x16) -> P packed in-register via
//   v_perm -> O^T += V^T·P^T. Fixed-max softmax (LN bounds |S|),
//   l = per-lane sum. End: halves combine through LDS (stride-33 floats).
// ---------------------------------------------------------------------------
__global__ __launch_bounds__(512, 4) void flash2_kernel(
    const short* __restrict__ Q, const short* __restrict__ K,
    const short* __restrict__ Vt, short* __restrict__ O)
{
  __shared__ __align__(16) long long smem8[8192];   // 64 KB
  short* Ks  = (short*)smem8;        // 4 bufs x 4096 shorts: [half*2+buf]
  short* Vts = Ks + 16384;
  float* scr = (float*)smem8;        // epilogue reuse

  const int tid = threadIdx.x;
  const int wave = tid >> 6, lane = tid & 63;
  const int half = wave >> 2, wg = wave & 3;
  const int hh = lane >> 5, q5 = lane & 31;
  const int qb = blockIdx.x, h = blockIdx.y, b = blockIdx.z;
  const int q0 = qb * 128 + wg * 32;

  const size_t kbase = ((size_t)b * 2048) * 1024 + (size_t)h * 64;
  const size_t vbase = ((size_t)h * 64) * 4096 + (size_t)b * 2048;

  // Q B-frags: lane holds Q[q0+q5][c*16 + hh*8 + j]
  bf16x8 qf[4];
  {
    const size_t qrow = ((size_t)b * 2048 + q0 + q5) * 1024 + (size_t)h * 64;
#pragma unroll
    for (int c = 0; c < 4; c++)
      qf[c] = *(const bf16x8*)(Q + qrow + c * 16 + hh * 8);
  }

  f32x16 oacc[2];
#pragma unroll
  for (int mt = 0; mt < 2; mt++)
#pragma unroll
    for (int t = 0; t < 16; t++) oacc[mt][t] = 0.f;
  float lsum = 0.f;

  // staging: within a half, 4 waves each cover 16 rows; XOR-swizzled source
  const int srow = lane >> 3;
  const int csrc = ((lane & 7) ^ srow) * 8;
  const int wr0 = wg * 16;

#define STAGE(bufi, kt)                                                         \
  {                                                                             \
    const short* ks = K + kbase + (size_t)((kt) * 64 + wr0 + srow) * 1024 + csrc; \
    const short* vs = Vt + vbase + (size_t)(wr0 + srow) * 4096 + (kt) * 64 + csrc; \
    short* kd = Ks  + (half * 2 + (bufi)) * 4096 + wr0 * 64;                    \
    short* vd = Vts + (half * 2 + (bufi)) * 4096 + wr0 * 64;                    \
    gl_lds16(ks,            kd);                                                \
    gl_lds16(ks + 8 * 1024, kd + 512);                                          \
    gl_lds16(vs,            vd);                                                \
    gl_lds16(vs + 8 * 4096, vd + 512);                                          \
  }

  STAGE(0, half)

  for (int i = 0; i < 16; i++){
    const int buf = i & 1;
    __syncthreads();                         // staging(buf) drained; buf^1 free
    if (i + 1 < 16) STAGE(buf ^ 1, 2 * (i + 1) + half)

    const short* kb_l = Ks  + (half * 2 + buf) * 4096;
    const short* vb_l = Vts + (half * 2 + buf) * 4096;

#pragma unroll
    for (int s32 = 0; s32 < 2; s32++){
      // ---- S^T = K·Q^T ----
      f32x16 sacc;
#pragma unroll
      for (int t = 0; t < 16; t++) sacc[t] = 0.f;
      const int key = s32 * 32 + q5;
#pragma unroll
      for (int c = 0; c < 4; c++){
        bf16x8 kf = *(const bf16x8*)(&kb_l[key * 64 + (((2*c + hh) ^ (key & 7)) << 3)]);
        sacc = __builtin_amdgcn_mfma_f32_32x32x16_bf16(kf, qf[c], sacc, 0, 0, 0);
      }

      // ---- P = exp2(S^T*scale); pack to bf16 via bit-add + v_perm ----
      unsigned int pu[16];
#pragma unroll
      for (int t = 0; t < 16; t++){
        const float e = __builtin_amdgcn_exp2f(sacc[t] * 0.18033688f);
        lsum += e;
        unsigned int u; __builtin_memcpy(&u, &e, 4);
        pu[t] = u + 0x8000u;                 // round-half-up into top 16 bits
      }

      // ---- O^T += V^T·P^T (pf built directly in permuted order) ----
#pragma unroll
      for (int c = 0; c < 2; c++){
        u32x4 tmp;
        tmp[0] = __builtin_amdgcn_perm(pu[4*c + 1], pu[4*c + 0], 0x07060302u);
        tmp[1] = __builtin_amdgcn_perm(pu[4*c + 3], pu[4*c + 2], 0x07060302u);
        tmp[2] = __builtin_amdgcn_perm(pu[8 + 4*c + 1], pu[8 + 4*c + 0], 0x07060302u);
        tmp[3] = __builtin_amdgcn_perm(pu[8 + 4*c + 3], pu[8 + 4*c + 2], 0x07060302u);
        bf16x8 pf; __builtin_memcpy(&pf, &tmp, 16);
#pragma unroll
        for (int mt = 0; mt < 2; mt++){
          const int d = mt * 32 + q5;
          bf16x8 vf = *(const bf16x8*)(&vb_l[d * 64 + (((s32*4 + 2*c + hh) ^ (d & 7)) << 3)]);
          oacc[mt] = __builtin_amdgcn_mfma_f32_32x32x16_bf16(vf, pf, oacc[mt], 0, 0, 0);
        }
      }
    }
  }

  // ---- combine halves through LDS, then store O[q][d] = O^T / l ----
  lsum += __shfl_xor(lsum, 32);
  __syncthreads();                           // all buffer reads done
  float* base = scr + (wg * 64 + lane) * 33;
  if (half == 1){
#pragma unroll
    for (int t = 0; t < 16; t++){ base[t] = oacc[0][t]; base[16 + t] = oacc[1][t]; }
    scr[8448 + wg * 64 + lane] = lsum;
  }
  __syncthreads();
  if (half == 0){
    const float l2 = scr[8448 + wg * 64 + lane];
    const float linv = 1.0f / (lsum + l2);
    const size_t orow = ((size_t)b * 2048 + q0 + q5) * 1024 + (size_t)h * 64;
#pragma unroll
    for (int mt = 0; mt < 2; mt++){
#pragma unroll
      for (int g = 0; g < 4; g++){
        bf16x4 o4;
#pragma unroll
        for (int u = 0; u < 4; u++)
          o4[u] = f2b((oacc[mt][g*4 + u] + base[mt*16 + g*4 + u]) * linv);
        *(bf16x4*)(O + orow + mt*32 + g*8 + 4*hh) = o4;
      }
    }
  }
}
#undef STAGE

// ---------------------------------------------------------------------------
extern "C" void kernel_launch(void* const* d_in, const int* in_sizes, int n_in,
                              void* d_out, int out_size, void* d_ws, size_t ws_size,
                              hipStream_t stream) {
  const float* emb  = (const float*)d_in[0];
  const float* ctx  = (const float*)d_in[1];
  const float* Wq   = (const float*)d_in[2];
  const float* Wk   = (const float*)d_in[3];
  const float* Wv   = (const float*)d_in[4];
  const float* Wu   = (const float*)d_in[5];
  const float* bu   = (const float*)d_in[6];
  const float* qn_w = (const float*)d_in[7];
  const float* qn_b = (const float*)d_in[8];
  const float* kn_w = (const float*)d_in[9];
  const float* kn_b = (const float*)d_in[10];
  float* out = (float*)d_out;

  const size_t BIG = (size_t)4096 * 1024;
  const size_t WSZ = (size_t)1024 * 1024;
  short* ws   = (short*)d_ws;
  short* embh = ws;
  short* ctxh = embh + BIG;
  short* Wqh  = ctxh + BIG;
  short* Wkh  = Wqh + WSZ;
  short* Wvh  = Wkh + WSZ;
  short* Wuh  = Wvh + WSZ;
  short* qh   = Wuh + WSZ;
  short* kh   = qh + BIG;
  short* vth  = kh + BIG;    // V^T [inner][token], key-permuted columns
  short* aoh  = vth + BIG;

  cvt6_kernel<<<12288, 256, 0, stream>>>(emb, ctx, Wq, Wk, Wv, Wu,
                                         embh, ctxh, Wqh, Wkh, Wvh, Wuh);

  gemm_qkv_kernel<<<dim3(256, 3), 256, 0, stream>>>(
      embh, ctxh, Wqh, Wkh, Wvh, qh, kh, vth,
      qn_w, qn_b, kn_w, kn_b);

  flash2_kernel<<<dim3(16, 16, 2), 512, 0, stream>>>(qh, kh, vth, aoh);

  gemm_out_kernel<<<dim3(8, 32), 256, 0, stream>>>(aoh, Wuh, out, bu);
}

// Round 5
// 219.237 us; speedup vs baseline: 4.8663x; 1.0576x over previous
//
#include <hip/hip_runtime.h>

// ============================================================================
// MultiHeadCrossAttention on MI355X (gfx950) — round 5
//   B=2, SQ=SK=2048, H=16, D=64, EMB=CTX=INNER=1024, fp32 in/out.
//
// 4 dispatches:
//   1. cvt6: all fp32->bf16 conversions
//   2. gemm_qkv (768 blocks, 3 tasks, XCD-local block maps): q,k (+fused LN),
//      vT (key-permuted cols)
//   3. flash2: 8-wave blocks, 2-way K-split, S^T=K·Q^T (32x32x16), P packed
//      in-register, O^T=V^T·P^T; grid h-innermost for per-XCD K/V L2 reuse
//   4. gemm_out: 512 threads, in-block split-K x2 (halves own K-range +
//      private LDS), LDS fp32 combine + bias; bm-fastest for XCD locality
// ============================================================================

typedef __attribute__((ext_vector_type(8)))  short bf16x8;
typedef __attribute__((ext_vector_type(4)))  short bf16x4;
typedef __attribute__((ext_vector_type(4)))  float f32x4;
typedef __attribute__((ext_vector_type(16))) float f32x16;
typedef __attribute__((ext_vector_type(4)))  unsigned int u32x4;

typedef __attribute__((address_space(1))) const void cg_void;
typedef __attribute__((address_space(3))) void lds_void_t;

__device__ __forceinline__ void gl_lds16(const void* g, void* l){
  __builtin_amdgcn_global_load_lds((cg_void*)g, (lds_void_t*)l, 16, 0, 0);
}

__device__ __forceinline__ short f2b(float f){
  unsigned int u;
  __builtin_memcpy(&u, &f, 4);
  u += 0x7fffu + ((u >> 16) & 1u);   // round-to-nearest-even
  return (short)(u >> 16);
}

// ---------------------------------------------------------------------------
// Fused fp32 -> bf16 convert of all six inputs (12M elems, 4 per thread).
// ---------------------------------------------------------------------------
__global__ __launch_bounds__(256) void cvt6_kernel(
    const float* __restrict__ emb, const float* __restrict__ ctx,
    const float* __restrict__ Wq, const float* __restrict__ Wk,
    const float* __restrict__ Wv, const float* __restrict__ Wu,
    short* __restrict__ o_emb, short* __restrict__ o_ctx,
    short* __restrict__ o_wq, short* __restrict__ o_wk,
    short* __restrict__ o_wv, short* __restrict__ o_wu)
{
  const long M1 = 1024L * 1024L, M4 = 4L * M1;
  long e = ((long)blockIdx.x * 256 + threadIdx.x) * 4;
  if (e >= 12L * M1) return;
  const float* src; short* dst; long off;
  if      (e <     M4)      { src = emb; dst = o_emb; off = e;           }
  else if (e < 2 * M4)      { src = ctx; dst = o_ctx; off = e - M4;      }
  else if (e < 2 * M4 + M1) { src = Wq;  dst = o_wq;  off = e - 2 * M4;  }
  else if (e < 2 * M4 + 2*M1){src = Wk;  dst = o_wk;  off = e - 2*M4 - M1;}
  else if (e < 2 * M4 + 3*M1){src = Wv;  dst = o_wv;  off = e - 2*M4 - 2*M1;}
  else                      { src = Wu;  dst = o_wu;  off = e - 2*M4 - 3*M1;}
  f32x4 v = *(const f32x4*)(src + off);
  bf16x4 o;
  o[0] = f2b(v[0]); o[1] = f2b(v[1]); o[2] = f2b(v[2]); o[3] = f2b(v[3]);
  *(bf16x4*)(dst + off) = o;
}

// ---------------------------------------------------------------------------
// Fused QKV projections. Grid (256, 3); blockIdx.y = task.
//   task 0: q = emb@Wq^T + LN   (bm = x&31 fastest -> same-A blocks share XCD)
//   task 1: k = ctx@Wk^T + LN   (same tiling)
//   task 2: vT = Wv@ctx^T, key-permuted columns (bn = x&31 fastest -> same-B
//           blocks share XCD; B=ctx is the big operand here)
// 128x128 tile, BK=64, 4 waves 2x2, MFMA 16x16x32, gl_lds staging (m97).
// ---------------------------------------------------------------------------
__global__ __launch_bounds__(256) void gemm_qkv_kernel(
    const short* __restrict__ embh, const short* __restrict__ ctxh,
    const short* __restrict__ Wqh, const short* __restrict__ Wkh,
    const short* __restrict__ Wvh,
    short* __restrict__ qo, short* __restrict__ ko, short* __restrict__ vto,
    const float* __restrict__ qw, const float* __restrict__ qb,
    const float* __restrict__ kw, const float* __restrict__ kb)
{
  const int K = 1024;
  __shared__ short As[128 * 64];
  __shared__ short Bs[128 * 64];
  const int tid  = threadIdx.x;
  const int wave = tid >> 6, lane = tid & 63;
  const int quad = lane >> 4, r16 = lane & 15;
  const int wm = (wave >> 1) * 64, wn = (wave & 1) * 64;

  const int task = blockIdx.y;
  int bn, bm, N;
  const short *A, *B;
  if (task == 2){
    bn = (blockIdx.x & 31) * 128; bm = (blockIdx.x >> 5) * 128; N = 4096;
    A = Wvh; B = ctxh;
  } else {
    // bm fastest: x%8 == bm%8 -> the 8 bn-blocks of one A-tile share an XCD
    bm = (blockIdx.x & 31) * 128; bn = (blockIdx.x >> 5) * 128; N = 1024;
    A = task ? ctxh : embh; B = task ? Wkh : Wqh;
  }

  f32x4 acc[4][4];
#pragma unroll
  for (int i = 0; i < 4; i++)
#pragma unroll
    for (int j = 0; j < 4; j++)
      acc[i][j] = (f32x4){0.f, 0.f, 0.f, 0.f};

  const size_t arow = (size_t)(bm + wave * 8 + (lane >> 3)) * K + (lane & 7) * 8;
  const size_t brow = (size_t)(bn + wave * 8 + (lane >> 3)) * K + (lane & 7) * 8;

  for (int k0 = 0; k0 < K; k0 += 64){
#pragma unroll
    for (int i = 0; i < 4; i++){
      gl_lds16(A + arow + (size_t)32 * i * K + k0, &As[wave * 512 + i * 2048]);
      gl_lds16(B + brow + (size_t)32 * i * K + k0, &Bs[wave * 512 + i * 2048]);
    }
    __syncthreads();
#pragma unroll
    for (int kk = 0; kk < 2; kk++){
      bf16x8 af[4], bq[4];
#pragma unroll
      for (int i = 0; i < 4; i++)
        af[i] = *(const bf16x8*)(&As[(wm + i*16 + r16) * 64 + kk*32 + quad*8]);
#pragma unroll
      for (int j = 0; j < 4; j++)
        bq[j] = *(const bf16x8*)(&Bs[(wn + j*16 + r16) * 64 + kk*32 + quad*8]);
#pragma unroll
      for (int i = 0; i < 4; i++)
#pragma unroll
        for (int j = 0; j < 4; j++)
          acc[i][j] = __builtin_amdgcn_mfma_f32_16x16x32_bf16(af[i], bq[j], acc[i][j], 0, 0, 0);
    }
    __syncthreads();
  }

  if (task < 2){
    short* Ch = task ? ko : qo;
    const float* lw = task ? kw : qw;
    const float* lb = task ? kb : qb;
    float wv[4], bv[4];
#pragma unroll
    for (int j = 0; j < 4; j++){ wv[j] = lw[j*16 + r16]; bv[j] = lb[j*16 + r16]; }
#pragma unroll
    for (int i = 0; i < 4; i++){
#pragma unroll
      for (int t = 0; t < 4; t++){
        float a[4];
#pragma unroll
        for (int j = 0; j < 4; j++) a[j] = acc[i][j][t];
        float s = a[0] + a[1] + a[2] + a[3];
        s += __shfl_xor(s, 1); s += __shfl_xor(s, 2);
        s += __shfl_xor(s, 4); s += __shfl_xor(s, 8);
        const float mu = s * 0.015625f;
        float d[4], sq = 0.f;
#pragma unroll
        for (int j = 0; j < 4; j++){ d[j] = a[j] - mu; sq += d[j]*d[j]; }
        sq += __shfl_xor(sq, 1); sq += __shfl_xor(sq, 2);
        sq += __shfl_xor(sq, 4); sq += __shfl_xor(sq, 8);
        const float si = rsqrtf(sq * 0.015625f + 1e-5f);
        const size_t row = (size_t)(bm + wm + i*16 + quad*4 + t);
#pragma unroll
        for (int j = 0; j < 4; j++)
          Ch[row * 1024 + (bn + wn + j*16 + r16)] = f2b(d[j] * si * wv[j] + bv[j]);
      }
    }
  } else {
#pragma unroll
    for (int i = 0; i < 4; i++){
#pragma unroll
      for (int j = 0; j < 4; j++){
        // permute token index within its 32-group into PV fragment order
        const int p = (r16 & 3) | ((j & 1) << 2) | (((r16 >> 2) & 1) << 3)
                      | (((r16 >> 3) & 1) << 4);
        const int col = ((bn + wn + j*16 + r16) & ~31) | p;
#pragma unroll
        for (int t = 0; t < 4; t++){
          const size_t row = (size_t)(bm + wm + i*16 + quad*4 + t);
          vto[row * (size_t)N + col] = f2b(acc[i][j][t]);
        }
      }
    }
  }
}

// ---------------------------------------------------------------------------
// out = ao @ Wu^T + bu. M=4096, N=K=1024, fp32 out.
// 512 threads = 8 waves: half = wave>>2 owns K range [half*512, +512), with a
// private 32 KB LDS pair -> 8 iters of BK=64, 8 waves/CU. Halves combine
// through LDS (stride-17 floats, 2-way max) with bias in the epilogue.
// Grid (32, 8): bm fastest -> same-A blocks share an XCD.
// ---------------------------------------------------------------------------
__global__ __launch_bounds__(512) void gemm_out_kernel(
    const short* __restrict__ A, const short* __restrict__ B,
    float* __restrict__ Cf, const float* __restrict__ bias)
{
  const int K = 1024, N = 1024;
  __shared__ short As[2][128 * 64];
  __shared__ short Bs[2][128 * 64];
  const int tid  = threadIdx.x;
  const int wave = tid >> 6, lane = tid & 63;
  const int half = wave >> 2, wg = wave & 3;
  const int quad = lane >> 4, r16 = lane & 15;
  const int wm = (wg >> 1) * 64, wn = (wg & 1) * 64;
  const int bm = blockIdx.x * 128, bn = blockIdx.y * 128;

  f32x4 acc[4][4];
#pragma unroll
  for (int i = 0; i < 4; i++)
#pragma unroll
    for (int j = 0; j < 4; j++)
      acc[i][j] = (f32x4){0.f, 0.f, 0.f, 0.f};

  const int kh = half * 512;
  const size_t arow = (size_t)(bm + wg * 8 + (lane >> 3)) * K + kh + (lane & 7) * 8;
  const size_t brow = (size_t)(bn + wg * 8 + (lane >> 3)) * K + kh + (lane & 7) * 8;

  for (int k0 = 0; k0 < 512; k0 += 64){
#pragma unroll
    for (int i = 0; i < 4; i++){
      gl_lds16(A + arow + (size_t)32 * i * K + k0, &As[half][wg * 512 + i * 2048]);
      gl_lds16(B + brow + (size_t)32 * i * K + k0, &Bs[half][wg * 512 + i * 2048]);
    }
    __syncthreads();
#pragma unroll
    for (int kk = 0; kk < 2; kk++){
      bf16x8 af[4], bq[4];
#pragma unroll
      for (int i = 0; i < 4; i++)
        af[i] = *(const bf16x8*)(&As[half][(wm + i*16 + r16) * 64 + kk*32 + quad*8]);
#pragma unroll
      for (int j = 0; j < 4; j++)
        bq[j] = *(const bf16x8*)(&Bs[half][(wn + j*16 + r16) * 64 + kk*32 + quad*8]);
#pragma unroll
      for (int i = 0; i < 4; i++)
#pragma unroll
        for (int j = 0; j < 4; j++)
          acc[i][j] = __builtin_amdgcn_mfma_f32_16x16x32_bf16(af[i], bq[j], acc[i][j], 0, 0, 0);
    }
    __syncthreads();
  }

  // ---- combine halves (4 rounds of one i-row each), +bias, store fp32 ----
  float* scr = (float*)&As[0][0];   // 64 KB scratch, free after K-loop sync
#pragma unroll
  for (int i = 0; i < 4; i++){
    if (half == 1){
      float* p = scr + (wg * 64 + lane) * 17;
#pragma unroll
      for (int j = 0; j < 4; j++)
#pragma unroll
        for (int t = 0; t < 4; t++) p[j*4 + t] = acc[i][j][t];
    }
    __syncthreads();
    if (half == 0){
      const float* p = scr + (wg * 64 + lane) * 17;
#pragma unroll
      for (int j = 0; j < 4; j++){
        const int col = bn + wn + j*16 + r16;
#pragma unroll
        for (int t = 0; t < 4; t++){
          const size_t row = (size_t)(bm + wm + i*16 + quad*4 + t);
          Cf[row * N + col] = acc[i][j][t] + p[j*4 + t] + bias[col];
        }
      }
    }
    __syncthreads();
  }
}

// ---------------------------------------------------------------------------
// MFMA flash attention v3 — 8 waves, 2-way K-split.
//   Grid (16 h, 16 qb, 2 b): h innermost -> all q-blocks of a head+batch on
//   one XCD (per-XCD K/V working set 2 MB < 4 MB L2).
//   wave = half*4 + wg: wg = query group (32 q), half = K-parity (even/odd kt).
//   Per half: double-buffered 64-key tiles (Ks [key][d], Vts [d][key_perm],
//   XOR-swizzled). S^T = K·Q^T (32x32x16) -> P packed in-register via
//   v_perm -> O^T += V^T·P^T. Fixed-max softmax (LN bounds |S|),
//   l = per-lane sum. End: halves combine through LDS (stride-33 floats).
// ---------------------------------------------------------------------------
__global__ __launch_bounds__(512, 4) void flash2_kernel(
    const short* __restrict__ Q, const short* __restrict__ K,
    const short* __restrict__ Vt, short* __restrict__ O)
{
  __shared__ __align__(16) long long smem8[8192];   // 64 KB
  short* Ks  = (short*)smem8;        // 4 bufs x 4096 shorts: [half*2+buf]
  short* Vts = Ks + 16384;
  float* scr = (float*)smem8;        // epilogue reuse

  const int tid = threadIdx.x;
  const int wave = tid >> 6, lane = tid & 63;
  const int half = wave >> 2, wg = wave & 3;
  const int hh = lane >> 5, q5 = lane & 31;
  const int h = blockIdx.x, qb = blockIdx.y, b = blockIdx.z;
  const int q0 = qb * 128 + wg * 32;

  const size_t kbase = ((size_t)b * 2048) * 1024 + (size_t)h * 64;
  const size_t vbase = ((size_t)h * 64) * 4096 + (size_t)b * 2048;

  // Q B-frags: lane holds Q[q0+q5][c*16 + hh*8 + j]
  bf16x8 qf[4];
  {
    const size_t qrow = ((size_t)b * 2048 + q0 + q5) * 1024 + (size_t)h * 64;
#pragma unroll
    for (int c = 0; c < 4; c++)
      qf[c] = *(const bf16x8*)(Q + qrow + c * 16 + hh * 8);
  }

  f32x16 oacc[2];
#pragma unroll
  for (int mt = 0; mt < 2; mt++)
#pragma unroll
    for (int t = 0; t < 16; t++) oacc[mt][t] = 0.f;
  float lsum = 0.f;

  // staging: within a half, 4 waves each cover 16 rows; XOR-swizzled source
  const int srow = lane >> 3;
  const int csrc = ((lane & 7) ^ srow) * 8;
  const int wr0 = wg * 16;

#define STAGE(bufi, kt)                                                         \
  {                                                                             \
    const short* ks = K + kbase + (size_t)((kt) * 64 + wr0 + srow) * 1024 + csrc; \
    const short* vs = Vt + vbase + (size_t)(wr0 + srow) * 4096 + (kt) * 64 + csrc; \
    short* kd = Ks  + (half * 2 + (bufi)) * 4096 + wr0 * 64;                    \
    short* vd = Vts + (half * 2 + (bufi)) * 4096 + wr0 * 64;                    \
    gl_lds16(ks,            kd);                                                \
    gl_lds16(ks + 8 * 1024, kd + 512);                                          \
    gl_lds16(vs,            vd);                                                \
    gl_lds16(vs + 8 * 4096, vd + 512);                                          \
  }

  STAGE(0, half)

  for (int i = 0; i < 16; i++){
    const int buf = i & 1;
    __syncthreads();                         // staging(buf) drained; buf^1 free
    if (i + 1 < 16) STAGE(buf ^ 1, 2 * (i + 1) + half)

    const short* kb_l = Ks  + (half * 2 + buf) * 4096;
    const short* vb_l = Vts + (half * 2 + buf) * 4096;

#pragma unroll
    for (int s32 = 0; s32 < 2; s32++){
      // ---- S^T = K·Q^T ----
      f32x16 sacc;
#pragma unroll
      for (int t = 0; t < 16; t++) sacc[t] = 0.f;
      const int key = s32 * 32 + q5;
#pragma unroll
      for (int c = 0; c < 4; c++){
        bf16x8 kf = *(const bf16x8*)(&kb_l[key * 64 + (((2*c + hh) ^ (key & 7)) << 3)]);
        sacc = __builtin_amdgcn_mfma_f32_32x32x16_bf16(kf, qf[c], sacc, 0, 0, 0);
      }

      // ---- P = exp2(S^T*scale); pack to bf16 via bit-add + v_perm ----
      unsigned int pu[16];
#pragma unroll
      for (int t = 0; t < 16; t++){
        const float e = __builtin_amdgcn_exp2f(sacc[t] * 0.18033688f);
        lsum += e;
        unsigned int u; __builtin_memcpy(&u, &e, 4);
        pu[t] = u + 0x8000u;                 // round-half-up into top 16 bits
      }

      // ---- O^T += V^T·P^T (pf built directly in permuted order) ----
#pragma unroll
      for (int c = 0; c < 2; c++){
        u32x4 tmp;
        tmp[0] = __builtin_amdgcn_perm(pu[4*c + 1], pu[4*c + 0], 0x07060302u);
        tmp[1] = __builtin_amdgcn_perm(pu[4*c + 3], pu[4*c + 2], 0x07060302u);
        tmp[2] = __builtin_amdgcn_perm(pu[8 + 4*c + 1], pu[8 + 4*c + 0], 0x07060302u);
        tmp[3] = __builtin_amdgcn_perm(pu[8 + 4*c + 3], pu[8 + 4*c + 2], 0x07060302u);
        bf16x8 pf; __builtin_memcpy(&pf, &tmp, 16);
#pragma unroll
        for (int mt = 0; mt < 2; mt++){
          const int d = mt * 32 + q5;
          bf16x8 vf = *(const bf16x8*)(&vb_l[d * 64 + (((s32*4 + 2*c + hh) ^ (d & 7)) << 3)]);
          oacc[mt] = __builtin_amdgcn_mfma_f32_32x32x16_bf16(vf, pf, oacc[mt], 0, 0, 0);
        }
      }
    }
  }

  // ---- combine halves through LDS, then store O[q][d] = O^T / l ----
  lsum += __shfl_xor(lsum, 32);
  __syncthreads();                           // all buffer reads done
  float* base = scr + (wg * 64 + lane) * 33;
  if (half == 1){
#pragma unroll
    for (int t = 0; t < 16; t++){ base[t] = oacc[0][t]; base[16 + t] = oacc[1][t]; }
    scr[8448 + wg * 64 + lane] = lsum;
  }
  __syncthreads();
  if (half == 0){
    const float l2 = scr[8448 + wg * 64 + lane];
    const float linv = 1.0f / (lsum + l2);
    const size_t orow = ((size_t)b * 2048 + q0 + q5) * 1024 + (size_t)h * 64;
#pragma unroll
    for (int mt = 0; mt < 2; mt++){
#pragma unroll
      for (int g = 0; g < 4; g++){
        bf16x4 o4;
#pragma unroll
        for (int u = 0; u < 4; u++)
          o4[u] = f2b((oacc[mt][g*4 + u] + base[mt*16 + g*4 + u]) * linv);
        *(bf16x4*)(O + orow + mt*32 + g*8 + 4*hh) = o4;
      }
    }
  }
}
#undef STAGE

// ---------------------------------------------------------------------------
extern "C" void kernel_launch(void* const* d_in, const int* in_sizes, int n_in,
                              void* d_out, int out_size, void* d_ws, size_t ws_size,
                              hipStream_t stream) {
  const float* emb  = (const float*)d_in[0];
  const float* ctx  = (const float*)d_in[1];
  const float* Wq   = (const float*)d_in[2];
  const float* Wk   = (const float*)d_in[3];
  const float* Wv   = (const float*)d_in[4];
  const float* Wu   = (const float*)d_in[5];
  const float* bu   = (const float*)d_in[6];
  const float* qn_w = (const float*)d_in[7];
  const float* qn_b = (const float*)d_in[8];
  const float* kn_w = (const float*)d_in[9];
  const float* kn_b = (const float*)d_in[10];
  float* out = (float*)d_out;

  const size_t BIG = (size_t)4096 * 1024;
  const size_t WSZ = (size_t)1024 * 1024;
  short* ws   = (short*)d_ws;
  short* embh = ws;
  short* ctxh = embh + BIG;
  short* Wqh  = ctxh + BIG;
  short* Wkh  = Wqh + WSZ;
  short* Wvh  = Wkh + WSZ;
  short* Wuh  = Wvh + WSZ;
  short* qh   = Wuh + WSZ;
  short* kh   = qh + BIG;
  short* vth  = kh + BIG;    // V^T [inner][token], key-permuted columns
  short* aoh  = vth + BIG;

  cvt6_kernel<<<12288, 256, 0, stream>>>(emb, ctx, Wq, Wk, Wv, Wu,
                                         embh, ctxh, Wqh, Wkh, Wvh, Wuh);

  gemm_qkv_kernel<<<dim3(256, 3), 256, 0, stream>>>(
      embh, ctxh, Wqh, Wkh, Wvh, qh, kh, vth,
      qn_w, qn_b, kn_w, kn_b);

  flash2_kernel<<<dim3(16, 16, 2), 512, 0, stream>>>(qh, kh, vth, aoh);

  gemm_out_kernel<<<dim3(32, 8), 512, 0, stream>>>(aoh, Wuh, out, bu);
}

// Round 6
// 205.122 us; speedup vs baseline: 5.2012x; 1.0688x over previous
//
#include <hip/hip_runtime.h>

// ============================================================================
// MultiHeadCrossAttention on MI355X (gfx950) — round 6
//   B=2, SQ=SK=2048, H=16, D=64, EMB=CTX=INNER=1024, fp32 in/out.
//
// 4 dispatches:
//   1. cvt6: all fp32->bf16 conversions
//   2. gemm_qkv (768 blocks, 3 tasks, XCD-local maps, XOR-swizzled LDS):
//      q,k (+fused LN), vT (key-permuted cols)
//   3. flash2: 8-wave blocks, 2-way K-split, S^T=K·Q^T (32x32x16), P packed
//      in-register, O^T=V^T·P^T; h-innermost grid for per-XCD K/V L2 reuse
//   4. gemm_out: 512 threads, in-block split-K x2, XOR-swizzled LDS,
//      LDS fp32 combine + bias
//
// Round-6 change: XOR swizzle (chunk ^= row&7) on BOTH GEMM kernels' LDS
// staging+reads — kills the 16-way quartet conflicts of the [row][k]
// 128B-stride layout (9.4e6 conflict-cycles in qkv alone at R5).
// ============================================================================

typedef __attribute__((ext_vector_type(8)))  short bf16x8;
typedef __attribute__((ext_vector_type(4)))  short bf16x4;
typedef __attribute__((ext_vector_type(4)))  float f32x4;
typedef __attribute__((ext_vector_type(16))) float f32x16;
typedef __attribute__((ext_vector_type(4)))  unsigned int u32x4;

typedef __attribute__((address_space(1))) const void cg_void;
typedef __attribute__((address_space(3))) void lds_void_t;

__device__ __forceinline__ void gl_lds16(const void* g, void* l){
  __builtin_amdgcn_global_load_lds((cg_void*)g, (lds_void_t*)l, 16, 0, 0);
}

__device__ __forceinline__ short f2b(float f){
  unsigned int u;
  __builtin_memcpy(&u, &f, 4);
  u += 0x7fffu + ((u >> 16) & 1u);   // round-to-nearest-even
  return (short)(u >> 16);
}

// ---------------------------------------------------------------------------
// Fused fp32 -> bf16 convert of all six inputs (12M elems, 4 per thread).
// ---------------------------------------------------------------------------
__global__ __launch_bounds__(256) void cvt6_kernel(
    const float* __restrict__ emb, const float* __restrict__ ctx,
    const float* __restrict__ Wq, const float* __restrict__ Wk,
    const float* __restrict__ Wv, const float* __restrict__ Wu,
    short* __restrict__ o_emb, short* __restrict__ o_ctx,
    short* __restrict__ o_wq, short* __restrict__ o_wk,
    short* __restrict__ o_wv, short* __restrict__ o_wu)
{
  const long M1 = 1024L * 1024L, M4 = 4L * M1;
  long e = ((long)blockIdx.x * 256 + threadIdx.x) * 4;
  if (e >= 12L * M1) return;
  const float* src; short* dst; long off;
  if      (e <     M4)      { src = emb; dst = o_emb; off = e;           }
  else if (e < 2 * M4)      { src = ctx; dst = o_ctx; off = e - M4;      }
  else if (e < 2 * M4 + M1) { src = Wq;  dst = o_wq;  off = e - 2 * M4;  }
  else if (e < 2 * M4 + 2*M1){src = Wk;  dst = o_wk;  off = e - 2*M4 - M1;}
  else if (e < 2 * M4 + 3*M1){src = Wv;  dst = o_wv;  off = e - 2*M4 - 2*M1;}
  else                      { src = Wu;  dst = o_wu;  off = e - 2*M4 - 3*M1;}
  f32x4 v = *(const f32x4*)(src + off);
  bf16x4 o;
  o[0] = f2b(v[0]); o[1] = f2b(v[1]); o[2] = f2b(v[2]); o[3] = f2b(v[3]);
  *(bf16x4*)(dst + off) = o;
}

// ---------------------------------------------------------------------------
// Fused QKV projections. Grid (256, 3); blockIdx.y = task.
//   task 0: q = emb@Wq^T + LN   (bm fastest -> same-A blocks share XCD)
//   task 1: k = ctx@Wk^T + LN
//   task 2: vT = Wv@ctx^T, key-permuted columns (bn fastest; B=ctx is big)
// 128x128 tile, BK=64, 4 waves 2x2, MFMA 16x16x32, gl_lds staging.
// LDS layout XOR-swizzled: LDS[row][c] holds global chunk c^(row&7)
// (swizzle applied on the gl_lds SOURCE address; reads use ((chunk)^(r&7)).
// ---------------------------------------------------------------------------
__global__ __launch_bounds__(256) void gemm_qkv_kernel(
    const short* __restrict__ embh, const short* __restrict__ ctxh,
    const short* __restrict__ Wqh, const short* __restrict__ Wkh,
    const short* __restrict__ Wvh,
    short* __restrict__ qo, short* __restrict__ ko, short* __restrict__ vto,
    const float* __restrict__ qw, const float* __restrict__ qb,
    const float* __restrict__ kw, const float* __restrict__ kb)
{
  const int K = 1024;
  __shared__ short As[128 * 64];
  __shared__ short Bs[128 * 64];
  const int tid  = threadIdx.x;
  const int wave = tid >> 6, lane = tid & 63;
  const int quad = lane >> 4, r16 = lane & 15;
  const int wm = (wave >> 1) * 64, wn = (wave & 1) * 64;

  const int task = blockIdx.y;
  int bn, bm, N;
  const short *A, *B;
  if (task == 2){
    bn = (blockIdx.x & 31) * 128; bm = (blockIdx.x >> 5) * 128; N = 4096;
    A = Wvh; B = ctxh;
  } else {
    bm = (blockIdx.x & 31) * 128; bn = (blockIdx.x >> 5) * 128; N = 1024;
    A = task ? ctxh : embh; B = task ? Wkh : Wqh;
  }

  f32x4 acc[4][4];
#pragma unroll
  for (int i = 0; i < 4; i++)
#pragma unroll
    for (int j = 0; j < 4; j++)
      acc[i][j] = (f32x4){0.f, 0.f, 0.f, 0.f};

  // staging: lane covers LDS slot (row = wave*8 + (lane>>3) + 32i, c = lane&7)
  // source column is XOR-swizzled so LDS[row][c] = global chunk c^(row&7)
  const int sr7 = (lane >> 3) & 7;
  const size_t arow = (size_t)(bm + wave * 8 + (lane >> 3)) * K
                      + (((lane & 7) ^ sr7) * 8);
  const size_t brow = (size_t)(bn + wave * 8 + (lane >> 3)) * K
                      + (((lane & 7) ^ sr7) * 8);

  // fragment-read swizzled chunk offset (shorts): kk=0 -> sw, kk=1 -> sw^32
  const int sw = ((quad ^ (r16 & 7)) << 3);

  for (int k0 = 0; k0 < K; k0 += 64){
#pragma unroll
    for (int i = 0; i < 4; i++){
      gl_lds16(A + arow + (size_t)32 * i * K + k0, &As[wave * 512 + i * 2048]);
      gl_lds16(B + brow + (size_t)32 * i * K + k0, &Bs[wave * 512 + i * 2048]);
    }
    __syncthreads();
#pragma unroll
    for (int kk = 0; kk < 2; kk++){
      const int off = sw ^ (kk << 5);
      bf16x8 af[4], bq[4];
#pragma unroll
      for (int i = 0; i < 4; i++)
        af[i] = *(const bf16x8*)(&As[(wm + i*16 + r16) * 64 + off]);
#pragma unroll
      for (int j = 0; j < 4; j++)
        bq[j] = *(const bf16x8*)(&Bs[(wn + j*16 + r16) * 64 + off]);
#pragma unroll
      for (int i = 0; i < 4; i++)
#pragma unroll
        for (int j = 0; j < 4; j++)
          acc[i][j] = __builtin_amdgcn_mfma_f32_16x16x32_bf16(af[i], bq[j], acc[i][j], 0, 0, 0);
    }
    __syncthreads();
  }

  if (task < 2){
    short* Ch = task ? ko : qo;
    const float* lw = task ? kw : qw;
    const float* lb = task ? kb : qb;
    float wv[4], bv[4];
#pragma unroll
    for (int j = 0; j < 4; j++){ wv[j] = lw[j*16 + r16]; bv[j] = lb[j*16 + r16]; }
#pragma unroll
    for (int i = 0; i < 4; i++){
#pragma unroll
      for (int t = 0; t < 4; t++){
        float a[4];
#pragma unroll
        for (int j = 0; j < 4; j++) a[j] = acc[i][j][t];
        float s = a[0] + a[1] + a[2] + a[3];
        s += __shfl_xor(s, 1); s += __shfl_xor(s, 2);
        s += __shfl_xor(s, 4); s += __shfl_xor(s, 8);
        const float mu = s * 0.015625f;
        float d[4], sq = 0.f;
#pragma unroll
        for (int j = 0; j < 4; j++){ d[j] = a[j] - mu; sq += d[j]*d[j]; }
        sq += __shfl_xor(sq, 1); sq += __shfl_xor(sq, 2);
        sq += __shfl_xor(sq, 4); sq += __shfl_xor(sq, 8);
        const float si = rsqrtf(sq * 0.015625f + 1e-5f);
        const size_t row = (size_t)(bm + wm + i*16 + quad*4 + t);
#pragma unroll
        for (int j = 0; j < 4; j++)
          Ch[row * 1024 + (bn + wn + j*16 + r16)] = f2b(d[j] * si * wv[j] + bv[j]);
      }
    }
  } else {
#pragma unroll
    for (int i = 0; i < 4; i++){
#pragma unroll
      for (int j = 0; j < 4; j++){
        // permute token index within its 32-group into PV fragment order
        const int p = (r16 & 3) | ((j & 1) << 2) | (((r16 >> 2) & 1) << 3)
                      | (((r16 >> 3) & 1) << 4);
        const int col = ((bn + wn + j*16 + r16) & ~31) | p;
#pragma unroll
        for (int t = 0; t < 4; t++){
          const size_t row = (size_t)(bm + wm + i*16 + quad*4 + t);
          vto[row * (size_t)N + col] = f2b(acc[i][j][t]);
        }
      }
    }
  }
}

// ---------------------------------------------------------------------------
// out = ao @ Wu^T + bu. M=4096, N=K=1024, fp32 out.
// 512 threads = 8 waves: half = wave>>2 owns K range [half*512, +512), private
// 32 KB LDS pair -> 8 iters of BK=64. XOR-swizzled staging/reads (as qkv).
// Halves combine through LDS (stride-17 floats) with bias in the epilogue.
// Grid (32, 8): bm fastest -> same-A blocks share an XCD.
// ---------------------------------------------------------------------------
__global__ __launch_bounds__(512) void gemm_out_kernel(
    const short* __restrict__ A, const short* __restrict__ B,
    float* __restrict__ Cf, const float* __restrict__ bias)
{
  const int K = 1024, N = 1024;
  __shared__ short As[2][128 * 64];
  __shared__ short Bs[2][128 * 64];
  const int tid  = threadIdx.x;
  const int wave = tid >> 6, lane = tid & 63;
  const int half = wave >> 2, wg = wave & 3;
  const int quad = lane >> 4, r16 = lane & 15;
  const int wm = (wg >> 1) * 64, wn = (wg & 1) * 64;
  const int bm = blockIdx.x * 128, bn = blockIdx.y * 128;

  f32x4 acc[4][4];
#pragma unroll
  for (int i = 0; i < 4; i++)
#pragma unroll
    for (int j = 0; j < 4; j++)
      acc[i][j] = (f32x4){0.f, 0.f, 0.f, 0.f};

  const int kh = half * 512;
  const int sr7 = (lane >> 3) & 7;
  const size_t arow = (size_t)(bm + wg * 8 + (lane >> 3)) * K + kh
                      + (((lane & 7) ^ sr7) * 8);
  const size_t brow = (size_t)(bn + wg * 8 + (lane >> 3)) * K + kh
                      + (((lane & 7) ^ sr7) * 8);
  const int sw = ((quad ^ (r16 & 7)) << 3);

  for (int k0 = 0; k0 < 512; k0 += 64){
#pragma unroll
    for (int i = 0; i < 4; i++){
      gl_lds16(A + arow + (size_t)32 * i * K + k0, &As[half][wg * 512 + i * 2048]);
      gl_lds16(B + brow + (size_t)32 * i * K + k0, &Bs[half][wg * 512 + i * 2048]);
    }
    __syncthreads();
#pragma unroll
    for (int kk = 0; kk < 2; kk++){
      const int off = sw ^ (kk << 5);
      bf16x8 af[4], bq[4];
#pragma unroll
      for (int i = 0; i < 4; i++)
        af[i] = *(const bf16x8*)(&As[half][(wm + i*16 + r16) * 64 + off]);
#pragma unroll
      for (int j = 0; j < 4; j++)
        bq[j] = *(const bf16x8*)(&Bs[half][(wn + j*16 + r16) * 64 + off]);
#pragma unroll
      for (int i = 0; i < 4; i++)
#pragma unroll
        for (int j = 0; j < 4; j++)
          acc[i][j] = __builtin_amdgcn_mfma_f32_16x16x32_bf16(af[i], bq[j], acc[i][j], 0, 0, 0);
    }
    __syncthreads();
  }

  // ---- combine halves (one i-row per round), +bias, store fp32 ----
  float* scr = (float*)&As[0][0];   // 64 KB scratch, free after K-loop sync
#pragma unroll
  for (int i = 0; i < 4; i++){
    if (half == 1){
      float* p = scr + (wg * 64 + lane) * 17;
#pragma unroll
      for (int j = 0; j < 4; j++)
#pragma unroll
        for (int t = 0; t < 4; t++) p[j*4 + t] = acc[i][j][t];
    }
    __syncthreads();
    if (half == 0){
      const float* p = scr + (wg * 64 + lane) * 17;
#pragma unroll
      for (int j = 0; j < 4; j++){
        const int col = bn + wn + j*16 + r16;
#pragma unroll
        for (int t = 0; t < 4; t++){
          const size_t row = (size_t)(bm + wm + i*16 + quad*4 + t);
          Cf[row * N + col] = acc[i][j][t] + p[j*4 + t] + bias[col];
        }
      }
    }
    __syncthreads();
  }
}

// ---------------------------------------------------------------------------
// MFMA flash attention v3 — 8 waves, 2-way K-split.
//   Grid (16 h, 16 qb, 2 b): h innermost -> all q-blocks of a head+batch on
//   one XCD (per-XCD K/V working set 2 MB < 4 MB L2).
//   wave = half*4 + wg: wg = query group (32 q), half = K-parity (even/odd kt).
//   Per half: double-buffered 64-key tiles (Ks [key][d], Vts [d][key_perm],
//   XOR-swizzled). S^T = K·Q^T (32x32x16) -> P packed in-register via
//   v_perm -> O^T += V^T·P^T. Fixed-max softmax (LN bounds |S|),
//   l = per-lane sum. End: halves combine through LDS (stride-33 floats).
// ---------------------------------------------------------------------------
__global__ __launch_bounds__(512, 4) void flash2_kernel(
    const short* __restrict__ Q, const short* __restrict__ K,
    const short* __restrict__ Vt, short* __restrict__ O)
{
  __shared__ __align__(16) long long smem8[8192];   // 64 KB
  short* Ks  = (short*)smem8;        // 4 bufs x 4096 shorts: [half*2+buf]
  short* Vts = Ks + 16384;
  float* scr = (float*)smem8;        // epilogue reuse

  const int tid = threadIdx.x;
  const int wave = tid >> 6, lane = tid & 63;
  const int half = wave >> 2, wg = wave & 3;
  const int hh = lane >> 5, q5 = lane & 31;
  const int h = blockIdx.x, qb = blockIdx.y, b = blockIdx.z;
  const int q0 = qb * 128 + wg * 32;

  const size_t kbase = ((size_t)b * 2048) * 1024 + (size_t)h * 64;
  const size_t vbase = ((size_t)h * 64) * 4096 + (size_t)b * 2048;

  // Q B-frags: lane holds Q[q0+q5][c*16 + hh*8 + j]
  bf16x8 qf[4];
  {
    const size_t qrow = ((size_t)b * 2048 + q0 + q5) * 1024 + (size_t)h * 64;
#pragma unroll
    for (int c = 0; c < 4; c++)
      qf[c] = *(const bf16x8*)(Q + qrow + c * 16 + hh * 8);
  }

  f32x16 oacc[2];
#pragma unroll
  for (int mt = 0; mt < 2; mt++)
#pragma unroll
    for (int t = 0; t < 16; t++) oacc[mt][t] = 0.f;
  float lsum = 0.f;

  // staging: within a half, 4 waves each cover 16 rows; XOR-swizzled source
  const int srow = lane >> 3;
  const int csrc = ((lane & 7) ^ srow) * 8;
  const int wr0 = wg * 16;

#define STAGE(bufi, kt)                                                         \
  {                                                                             \
    const short* ks = K + kbase + (size_t)((kt) * 64 + wr0 + srow) * 1024 + csrc; \
    const short* vs = Vt + vbase + (size_t)(wr0 + srow) * 4096 + (kt) * 64 + csrc; \
    short* kd = Ks  + (half * 2 + (bufi)) * 4096 + wr0 * 64;                    \
    short* vd = Vts + (half * 2 + (bufi)) * 4096 + wr0 * 64;                    \
    gl_lds16(ks,            kd);                                                \
    gl_lds16(ks + 8 * 1024, kd + 512);                                          \
    gl_lds16(vs,            vd);                                                \
    gl_lds16(vs + 8 * 4096, vd + 512);                                          \
  }

  STAGE(0, half)

  for (int i = 0; i < 16; i++){
    const int buf = i & 1;
    __syncthreads();                         // staging(buf) drained; buf^1 free
    if (i + 1 < 16) STAGE(buf ^ 1, 2 * (i + 1) + half)

    const short* kb_l = Ks  + (half * 2 + buf) * 4096;
    const short* vb_l = Vts + (half * 2 + buf) * 4096;

#pragma unroll
    for (int s32 = 0; s32 < 2; s32++){
      // ---- S^T = K·Q^T ----
      f32x16 sacc;
#pragma unroll
      for (int t = 0; t < 16; t++) sacc[t] = 0.f;
      const int key = s32 * 32 + q5;
#pragma unroll
      for (int c = 0; c < 4; c++){
        bf16x8 kf = *(const bf16x8*)(&kb_l[key * 64 + (((2*c + hh) ^ (key & 7)) << 3)]);
        sacc = __builtin_amdgcn_mfma_f32_32x32x16_bf16(kf, qf[c], sacc, 0, 0, 0);
      }

      // ---- P = exp2(S^T*scale); pack to bf16 via bit-add + v_perm ----
      unsigned int pu[16];
#pragma unroll
      for (int t = 0; t < 16; t++){
        const float e = __builtin_amdgcn_exp2f(sacc[t] * 0.18033688f);
        lsum += e;
        unsigned int u; __builtin_memcpy(&u, &e, 4);
        pu[t] = u + 0x8000u;                 // round-half-up into top 16 bits
      }

      // ---- O^T += V^T·P^T (pf built directly in permuted order) ----
#pragma unroll
      for (int c = 0; c < 2; c++){
        u32x4 tmp;
        tmp[0] = __builtin_amdgcn_perm(pu[4*c + 1], pu[4*c + 0], 0x07060302u);
        tmp[1] = __builtin_amdgcn_perm(pu[4*c + 3], pu[4*c + 2], 0x07060302u);
        tmp[2] = __builtin_amdgcn_perm(pu[8 + 4*c + 1], pu[8 + 4*c + 0], 0x07060302u);
        tmp[3] = __builtin_amdgcn_perm(pu[8 + 4*c + 3], pu[8 + 4*c + 2], 0x07060302u);
        bf16x8 pf; __builtin_memcpy(&pf, &tmp, 16);
#pragma unroll
        for (int mt = 0; mt < 2; mt++){
          const int d = mt * 32 + q5;
          bf16x8 vf = *(const bf16x8*)(&vb_l[d * 64 + (((s32*4 + 2*c + hh) ^ (d & 7)) << 3)]);
          oacc[mt] = __builtin_amdgcn_mfma_f32_32x32x16_bf16(vf, pf, oacc[mt], 0, 0, 0);
        }
      }
    }
  }

  // ---- combine halves through LDS, then store O[q][d] = O^T / l ----
  lsum += __shfl_xor(lsum, 32);
  __syncthreads();                           // all buffer reads done
  float* base = scr + (wg * 64 + lane) * 33;
  if (half == 1){
#pragma unroll
    for (int t = 0; t < 16; t++){ base[t] = oacc[0][t]; base[16 + t] = oacc[1][t]; }
    scr[8448 + wg * 64 + lane] = lsum;
  }
  __syncthreads();
  if (half == 0){
    const float l2 = scr[8448 + wg * 64 + lane];
    const float linv = 1.0f / (lsum + l2);
    const size_t orow = ((size_t)b * 2048 + q0 + q5) * 1024 + (size_t)h * 64;
#pragma unroll
    for (int mt = 0; mt < 2; mt++){
#pragma unroll
      for (int g = 0; g < 4; g++){
        bf16x4 o4;
#pragma unroll
        for (int u = 0; u < 4; u++)
          o4[u] = f2b((oacc[mt][g*4 + u] + base[mt*16 + g*4 + u]) * linv);
        *(bf16x4*)(O + orow + mt*32 + g*8 + 4*hh) = o4;
      }
    }
  }
}
#undef STAGE

// ---------------------------------------------------------------------------
extern "C" void kernel_launch(void* const* d_in, const int* in_sizes, int n_in,
                              void* d_out, int out_size, void* d_ws, size_t ws_size,
                              hipStream_t stream) {
  const float* emb  = (const float*)d_in[0];
  const float* ctx  = (const float*)d_in[1];
  const float* Wq   = (const float*)d_in[2];
  const float* Wk   = (const float*)d_in[3];
  const float* Wv   = (const float*)d_in[4];
  const float* Wu   = (const float*)d_in[5];
  const float* bu   = (const float*)d_in[6];
  const float* qn_w = (const float*)d_in[7];
  const float* qn_b = (const float*)d_in[8];
  const float* kn_w = (const float*)d_in[9];
  const float* kn_b = (const float*)d_in[10];
  float* out = (float*)d_out;

  const size_t BIG = (size_t)4096 * 1024;
  const size_t WSZ = (size_t)1024 * 1024;
  short* ws   = (short*)d_ws;
  short* embh = ws;
  short* ctxh = embh + BIG;
  short* Wqh  = ctxh + BIG;
  short* Wkh  = Wqh + WSZ;
  short* Wvh  = Wkh + WSZ;
  short* Wuh  = Wvh + WSZ;
  short* qh   = Wuh + WSZ;
  short* kh   = qh + BIG;
  short* vth  = kh + BIG;    // V^T [inner][token], key-permuted columns
  short* aoh  = vth + BIG;

  cvt6_kernel<<<12288, 256, 0, stream>>>(emb, ctx, Wq, Wk, Wv, Wu,
                                         embh, ctxh, Wqh, Wkh, Wvh, Wuh);

  gemm_qkv_kernel<<<dim3(256, 3), 256, 0, stream>>>(
      embh, ctxh, Wqh, Wkh, Wvh, qh, kh, vth,
      qn_w, qn_b, kn_w, kn_b);

  flash2_kernel<<<dim3(16, 16, 2), 512, 0, stream>>>(qh, kh, vth, aoh);

  gemm_out_kernel<<<dim3(32, 8), 512, 0, stream>>>(aoh, Wuh, out, bu);
}

// Round 7
// 199.800 us; speedup vs baseline: 5.3397x; 1.0266x over previous
//
#include <hip/hip_runtime.h>

// ============================================================================
// MultiHeadCrossAttention on MI355X (gfx950) — round 7
//   B=2, SQ=SK=2048, H=16, D=64, EMB=CTX=INNER=1024, fp32 in/out.
//
// 4 dispatches:
//   1. cvt6: all fp32->bf16 conversions
//   2. gemm_qkv (768 blocks, 3 tasks, XCD-local maps, XOR-swizzled LDS):
//      q (softmax scale pre-folded) ,k (+fused LN), vT (key-permuted cols)
//   3. flash2: 8-wave blocks, 2-way K-split, interleaved dual S^T chains,
//      exp2 direct (scale baked into q), P packed in-register, O^T=V^T·P^T
//   4. gemm_out: 1024 threads, 4-way in-block split-K (quarters own K/4,
//      private LDS), 4-way LDS combine + bias
// ============================================================================

typedef __attribute__((ext_vector_type(8)))  short bf16x8;
typedef __attribute__((ext_vector_type(4)))  short bf16x4;
typedef __attribute__((ext_vector_type(4)))  float f32x4;
typedef __attribute__((ext_vector_type(16))) float f32x16;
typedef __attribute__((ext_vector_type(4)))  unsigned int u32x4;

#define SM_SCALE 0.18033688f   // 0.125 * log2(e), folded into q at LN

typedef __attribute__((address_space(1))) const void cg_void;
typedef __attribute__((address_space(3))) void lds_void_t;

__device__ __forceinline__ void gl_lds16(const void* g, void* l){
  __builtin_amdgcn_global_load_lds((cg_void*)g, (lds_void_t*)l, 16, 0, 0);
}

__device__ __forceinline__ short f2b(float f){
  unsigned int u;
  __builtin_memcpy(&u, &f, 4);
  u += 0x7fffu + ((u >> 16) & 1u);   // round-to-nearest-even
  return (short)(u >> 16);
}

// ---------------------------------------------------------------------------
// Fused fp32 -> bf16 convert of all six inputs (12M elems, 4 per thread).
// ---------------------------------------------------------------------------
__global__ __launch_bounds__(256) void cvt6_kernel(
    const float* __restrict__ emb, const float* __restrict__ ctx,
    const float* __restrict__ Wq, const float* __restrict__ Wk,
    const float* __restrict__ Wv, const float* __restrict__ Wu,
    short* __restrict__ o_emb, short* __restrict__ o_ctx,
    short* __restrict__ o_wq, short* __restrict__ o_wk,
    short* __restrict__ o_wv, short* __restrict__ o_wu)
{
  const long M1 = 1024L * 1024L, M4 = 4L * M1;
  long e = ((long)blockIdx.x * 256 + threadIdx.x) * 4;
  if (e >= 12L * M1) return;
  const float* src; short* dst; long off;
  if      (e <     M4)      { src = emb; dst = o_emb; off = e;           }
  else if (e < 2 * M4)      { src = ctx; dst = o_ctx; off = e - M4;      }
  else if (e < 2 * M4 + M1) { src = Wq;  dst = o_wq;  off = e - 2 * M4;  }
  else if (e < 2 * M4 + 2*M1){src = Wk;  dst = o_wk;  off = e - 2*M4 - M1;}
  else if (e < 2 * M4 + 3*M1){src = Wv;  dst = o_wv;  off = e - 2*M4 - 2*M1;}
  else                      { src = Wu;  dst = o_wu;  off = e - 2*M4 - 3*M1;}
  f32x4 v = *(const f32x4*)(src + off);
  bf16x4 o;
  o[0] = f2b(v[0]); o[1] = f2b(v[1]); o[2] = f2b(v[2]); o[3] = f2b(v[3]);
  *(bf16x4*)(dst + off) = o;
}

// ---------------------------------------------------------------------------
// Fused QKV projections. Grid (256, 3); blockIdx.y = task.
//   task 0: q = (emb@Wq^T -> LN) * SM_SCALE   (scale folded into LN affine)
//   task 1: k = ctx@Wk^T + LN
//   task 2: vT = Wv@ctx^T, key-permuted columns
// 128x128 tile, BK=64, 4 waves 2x2, MFMA 16x16x32, gl_lds staging,
// XOR-swizzled LDS (chunk ^= row&7).
// ---------------------------------------------------------------------------
__global__ __launch_bounds__(256) void gemm_qkv_kernel(
    const short* __restrict__ embh, const short* __restrict__ ctxh,
    const short* __restrict__ Wqh, const short* __restrict__ Wkh,
    const short* __restrict__ Wvh,
    short* __restrict__ qo, short* __restrict__ ko, short* __restrict__ vto,
    const float* __restrict__ qw, const float* __restrict__ qb,
    const float* __restrict__ kw, const float* __restrict__ kb)
{
  const int K = 1024;
  __shared__ short As[128 * 64];
  __shared__ short Bs[128 * 64];
  const int tid  = threadIdx.x;
  const int wave = tid >> 6, lane = tid & 63;
  const int quad = lane >> 4, r16 = lane & 15;
  const int wm = (wave >> 1) * 64, wn = (wave & 1) * 64;

  const int task = blockIdx.y;
  int bn, bm, N;
  const short *A, *B;
  if (task == 2){
    bn = (blockIdx.x & 31) * 128; bm = (blockIdx.x >> 5) * 128; N = 4096;
    A = Wvh; B = ctxh;
  } else {
    bm = (blockIdx.x & 31) * 128; bn = (blockIdx.x >> 5) * 128; N = 1024;
    A = task ? ctxh : embh; B = task ? Wkh : Wqh;
  }

  f32x4 acc[4][4];
#pragma unroll
  for (int i = 0; i < 4; i++)
#pragma unroll
    for (int j = 0; j < 4; j++)
      acc[i][j] = (f32x4){0.f, 0.f, 0.f, 0.f};

  const int sr7 = (lane >> 3) & 7;
  const size_t arow = (size_t)(bm + wave * 8 + (lane >> 3)) * K
                      + (((lane & 7) ^ sr7) * 8);
  const size_t brow = (size_t)(bn + wave * 8 + (lane >> 3)) * K
                      + (((lane & 7) ^ sr7) * 8);
  const int sw = ((quad ^ (r16 & 7)) << 3);

  for (int k0 = 0; k0 < K; k0 += 64){
#pragma unroll
    for (int i = 0; i < 4; i++){
      gl_lds16(A + arow + (size_t)32 * i * K + k0, &As[wave * 512 + i * 2048]);
      gl_lds16(B + brow + (size_t)32 * i * K + k0, &Bs[wave * 512 + i * 2048]);
    }
    __syncthreads();
#pragma unroll
    for (int kk = 0; kk < 2; kk++){
      const int off = sw ^ (kk << 5);
      bf16x8 af[4], bq[4];
#pragma unroll
      for (int i = 0; i < 4; i++)
        af[i] = *(const bf16x8*)(&As[(wm + i*16 + r16) * 64 + off]);
#pragma unroll
      for (int j = 0; j < 4; j++)
        bq[j] = *(const bf16x8*)(&Bs[(wn + j*16 + r16) * 64 + off]);
#pragma unroll
      for (int i = 0; i < 4; i++)
#pragma unroll
        for (int j = 0; j < 4; j++)
          acc[i][j] = __builtin_amdgcn_mfma_f32_16x16x32_bf16(af[i], bq[j], acc[i][j], 0, 0, 0);
    }
    __syncthreads();
  }

  if (task < 2){
    short* Ch = task ? ko : qo;
    const float* lw = task ? kw : qw;
    const float* lb = task ? kb : qb;
    const float post = task ? 1.0f : SM_SCALE;   // fold softmax scale into q
    float wv[4], bv[4];
#pragma unroll
    for (int j = 0; j < 4; j++){
      wv[j] = lw[j*16 + r16] * post;
      bv[j] = lb[j*16 + r16] * post;
    }
#pragma unroll
    for (int i = 0; i < 4; i++){
#pragma unroll
      for (int t = 0; t < 4; t++){
        float a[4];
#pragma unroll
        for (int j = 0; j < 4; j++) a[j] = acc[i][j][t];
        float s = a[0] + a[1] + a[2] + a[3];
        s += __shfl_xor(s, 1); s += __shfl_xor(s, 2);
        s += __shfl_xor(s, 4); s += __shfl_xor(s, 8);
        const float mu = s * 0.015625f;
        float d[4], sq = 0.f;
#pragma unroll
        for (int j = 0; j < 4; j++){ d[j] = a[j] - mu; sq += d[j]*d[j]; }
        sq += __shfl_xor(sq, 1); sq += __shfl_xor(sq, 2);
        sq += __shfl_xor(sq, 4); sq += __shfl_xor(sq, 8);
        const float si = rsqrtf(sq * 0.015625f + 1e-5f);
        const size_t row = (size_t)(bm + wm + i*16 + quad*4 + t);
#pragma unroll
        for (int j = 0; j < 4; j++)
          Ch[row * 1024 + (bn + wn + j*16 + r16)] = f2b(d[j] * si * wv[j] + bv[j]);
      }
    }
  } else {
#pragma unroll
    for (int i = 0; i < 4; i++){
#pragma unroll
      for (int j = 0; j < 4; j++){
        // permute token index within its 32-group into PV fragment order
        const int p = (r16 & 3) | ((j & 1) << 2) | (((r16 >> 2) & 1) << 3)
                      | (((r16 >> 3) & 1) << 4);
        const int col = ((bn + wn + j*16 + r16) & ~31) | p;
#pragma unroll
        for (int t = 0; t < 4; t++){
          const size_t row = (size_t)(bm + wm + i*16 + quad*4 + t);
          vto[row * (size_t)N + col] = f2b(acc[i][j][t]);
        }
      }
    }
  }
}

// ---------------------------------------------------------------------------
// out = ao @ Wu^T + bu. M=4096, N=K=1024, fp32 out.
// 1024 threads = 16 waves: quarter = wave>>2 owns K range [qt*256, +256) with
// a private 32 KB LDS pair -> 4 iters of BK=64, 16 waves/CU (50% occupancy).
// XOR-swizzled staging/reads. 4-way combine through LDS (stride-17 floats).
// Grid (32, 8): bm fastest.
// ---------------------------------------------------------------------------
__global__ __launch_bounds__(1024, 4) void gemm_out_kernel(
    const short* __restrict__ A, const short* __restrict__ B,
    float* __restrict__ Cf, const float* __restrict__ bias)
{
  const int K = 1024, N = 1024;
  __shared__ short As[4][128 * 64];   // 64 KB
  __shared__ short Bs[4][128 * 64];   // 64 KB
  const int tid  = threadIdx.x;
  const int wave = tid >> 6, lane = tid & 63;
  const int qt = wave >> 2, wg = wave & 3;   // qt = K-quarter
  const int quad = lane >> 4, r16 = lane & 15;
  const int wm = (wg >> 1) * 64, wn = (wg & 1) * 64;
  const int bm = blockIdx.x * 128, bn = blockIdx.y * 128;

  f32x4 acc[4][4];
#pragma unroll
  for (int i = 0; i < 4; i++)
#pragma unroll
    for (int j = 0; j < 4; j++)
      acc[i][j] = (f32x4){0.f, 0.f, 0.f, 0.f};

  const int kh = qt * 256;
  const int sr7 = (lane >> 3) & 7;
  const size_t arow = (size_t)(bm + wg * 8 + (lane >> 3)) * K + kh
                      + (((lane & 7) ^ sr7) * 8);
  const size_t brow = (size_t)(bn + wg * 8 + (lane >> 3)) * K + kh
                      + (((lane & 7) ^ sr7) * 8);
  const int sw = ((quad ^ (r16 & 7)) << 3);

  for (int k0 = 0; k0 < 256; k0 += 64){
#pragma unroll
    for (int i = 0; i < 4; i++){
      gl_lds16(A + arow + (size_t)32 * i * K + k0, &As[qt][wg * 512 + i * 2048]);
      gl_lds16(B + brow + (size_t)32 * i * K + k0, &Bs[qt][wg * 512 + i * 2048]);
    }
    __syncthreads();
#pragma unroll
    for (int kk = 0; kk < 2; kk++){
      const int off = sw ^ (kk << 5);
      bf16x8 af[4], bq[4];
#pragma unroll
      for (int i = 0; i < 4; i++)
        af[i] = *(const bf16x8*)(&As[qt][(wm + i*16 + r16) * 64 + off]);
#pragma unroll
      for (int j = 0; j < 4; j++)
        bq[j] = *(const bf16x8*)(&Bs[qt][(wn + j*16 + r16) * 64 + off]);
#pragma unroll
      for (int i = 0; i < 4; i++)
#pragma unroll
        for (int j = 0; j < 4; j++)
          acc[i][j] = __builtin_amdgcn_mfma_f32_16x16x32_bf16(af[i], bq[j], acc[i][j], 0, 0, 0);
    }
    __syncthreads();
  }

  // ---- 4-way combine (one i-row per round), +bias, store fp32 ----
  float* scr = (float*)&As[0][0];   // 52 KB of the 64 KB As region
#pragma unroll
  for (int i = 0; i < 4; i++){
    if (qt != 0){
      float* p = scr + ((qt - 1) * 256 + wg * 64 + lane) * 17;
#pragma unroll
      for (int j = 0; j < 4; j++)
#pragma unroll
        for (int t = 0; t < 4; t++) p[j*4 + t] = acc[i][j][t];
    }
    __syncthreads();
    if (qt == 0){
      const float* p0 = scr + (wg * 64 + lane) * 17;
      const float* p1 = p0 + 256 * 17;
      const float* p2 = p1 + 256 * 17;
#pragma unroll
      for (int j = 0; j < 4; j++){
        const int col = bn + wn + j*16 + r16;
#pragma unroll
        for (int t = 0; t < 4; t++){
          const size_t row = (size_t)(bm + wm + i*16 + quad*4 + t);
          Cf[row * N + col] = acc[i][j][t] + p0[j*4+t] + p1[j*4+t] + p2[j*4+t]
                              + bias[col];
        }
      }
    }
    __syncthreads();
  }
}

// ---------------------------------------------------------------------------
// MFMA flash attention v4 — 8 waves, 2-way K-split, interleaved S chains.
//   Grid (16 h, 16 qb, 2 b): h innermost -> per-XCD K/V L2 reuse.
//   wave = half*4 + wg. Per half: double-buffered 64-key tiles (XOR-swizzled).
//   Per iteration: hoist all 8 kf reads, run the two 32-key S^T=K·Q^T chains
//   interleaved (2x MFMA ILP), then per s32: exp2 (scale pre-folded into q)
//   -> pack via v_perm -> O^T += V^T·P^T. l = per-lane sum.
//   End: halves combine through LDS (stride-33 floats).
// ---------------------------------------------------------------------------
__global__ __launch_bounds__(512, 4) void flash2_kernel(
    const short* __restrict__ Q, const short* __restrict__ K,
    const short* __restrict__ Vt, short* __restrict__ O)
{
  __shared__ __align__(16) long long smem8[8192];   // 64 KB
  short* Ks  = (short*)smem8;        // 4 bufs x 4096 shorts: [half*2+buf]
  short* Vts = Ks + 16384;
  float* scr = (float*)smem8;        // epilogue reuse

  const int tid = threadIdx.x;
  const int wave = tid >> 6, lane = tid & 63;
  const int half = wave >> 2, wg = wave & 3;
  const int hh = lane >> 5, q5 = lane & 31;
  const int h = blockIdx.x, qb = blockIdx.y, b = blockIdx.z;
  const int q0 = qb * 128 + wg * 32;

  const size_t kbase = ((size_t)b * 2048) * 1024 + (size_t)h * 64;
  const size_t vbase = ((size_t)h * 64) * 4096 + (size_t)b * 2048;

  // Q B-frags: lane holds Q[q0+q5][c*16 + hh*8 + j]  (pre-scaled by SM_SCALE)
  bf16x8 qf[4];
  {
    const size_t qrow = ((size_t)b * 2048 + q0 + q5) * 1024 + (size_t)h * 64;
#pragma unroll
    for (int c = 0; c < 4; c++)
      qf[c] = *(const bf16x8*)(Q + qrow + c * 16 + hh * 8);
  }

  f32x16 oacc[2];
#pragma unroll
  for (int mt = 0; mt < 2; mt++)
#pragma unroll
    for (int t = 0; t < 16; t++) oacc[mt][t] = 0.f;
  float lsum = 0.f;

  const int srow = lane >> 3;
  const int csrc = ((lane & 7) ^ srow) * 8;
  const int wr0 = wg * 16;

#define STAGE(bufi, kt)                                                         \
  {                                                                             \
    const short* ks = K + kbase + (size_t)((kt) * 64 + wr0 + srow) * 1024 + csrc; \
    const short* vs = Vt + vbase + (size_t)(wr0 + srow) * 4096 + (kt) * 64 + csrc; \
    short* kd = Ks  + (half * 2 + (bufi)) * 4096 + wr0 * 64;                    \
    short* vd = Vts + (half * 2 + (bufi)) * 4096 + wr0 * 64;                    \
    gl_lds16(ks,            kd);                                                \
    gl_lds16(ks + 8 * 1024, kd + 512);                                          \
    gl_lds16(vs,            vd);                                                \
    gl_lds16(vs + 8 * 4096, vd + 512);                                          \
  }

  STAGE(0, half)

  for (int i = 0; i < 16; i++){
    const int buf = i & 1;
    __syncthreads();                         // staging(buf) drained; buf^1 free
    if (i + 1 < 16) STAGE(buf ^ 1, 2 * (i + 1) + half)

    const short* kb_l = Ks  + (half * 2 + buf) * 4096;
    const short* vb_l = Vts + (half * 2 + buf) * 4096;

    // ---- hoist all 8 kf reads; run both 32-key S chains interleaved ----
    bf16x8 kf[2][4];
#pragma unroll
    for (int s32 = 0; s32 < 2; s32++){
      const int key = s32 * 32 + q5;
#pragma unroll
      for (int c = 0; c < 4; c++)
        kf[s32][c] = *(const bf16x8*)(&kb_l[key * 64 + (((2*c + hh) ^ (key & 7)) << 3)]);
    }
    f32x16 sacc[2];
#pragma unroll
    for (int t = 0; t < 16; t++){ sacc[0][t] = 0.f; sacc[1][t] = 0.f; }
#pragma unroll
    for (int c = 0; c < 4; c++){
      sacc[0] = __builtin_amdgcn_mfma_f32_32x32x16_bf16(kf[0][c], qf[c], sacc[0], 0, 0, 0);
      sacc[1] = __builtin_amdgcn_mfma_f32_32x32x16_bf16(kf[1][c], qf[c], sacc[1], 0, 0, 0);
    }

#pragma unroll
    for (int s32 = 0; s32 < 2; s32++){
      // ---- P = exp2(S^T) (scale pre-folded); pack via bit-add + v_perm ----
      unsigned int pu[16];
#pragma unroll
      for (int t = 0; t < 16; t++){
        const float e = __builtin_amdgcn_exp2f(sacc[s32][t]);
        lsum += e;
        unsigned int u; __builtin_memcpy(&u, &e, 4);
        pu[t] = u + 0x8000u;                 // round into top 16 bits
      }

      // ---- O^T += V^T·P^T (pf built directly in permuted order) ----
#pragma unroll
      for (int c = 0; c < 2; c++){
        u32x4 tmp;
        tmp[0] = __builtin_amdgcn_perm(pu[4*c + 1], pu[4*c + 0], 0x07060302u);
        tmp[1] = __builtin_amdgcn_perm(pu[4*c + 3], pu[4*c + 2], 0x07060302u);
        tmp[2] = __builtin_amdgcn_perm(pu[8 + 4*c + 1], pu[8 + 4*c + 0], 0x07060302u);
        tmp[3] = __builtin_amdgcn_perm(pu[8 + 4*c + 3], pu[8 + 4*c + 2], 0x07060302u);
        bf16x8 pf; __builtin_memcpy(&pf, &tmp, 16);
#pragma unroll
        for (int mt = 0; mt < 2; mt++){
          const int d = mt * 32 + q5;
          bf16x8 vf = *(const bf16x8*)(&vb_l[d * 64 + (((s32*4 + 2*c + hh) ^ (d & 7)) << 3)]);
          oacc[mt] = __builtin_amdgcn_mfma_f32_32x32x16_bf16(vf, pf, oacc[mt], 0, 0, 0);
        }
      }
    }
  }

  // ---- combine halves through LDS, then store O[q][d] = O^T / l ----
  lsum += __shfl_xor(lsum, 32);
  __syncthreads();                           // all buffer reads done
  float* base = scr + (wg * 64 + lane) * 33;
  if (half == 1){
#pragma unroll
    for (int t = 0; t < 16; t++){ base[t] = oacc[0][t]; base[16 + t] = oacc[1][t]; }
    scr[8448 + wg * 64 + lane] = lsum;
  }
  __syncthreads();
  if (half == 0){
    const float l2 = scr[8448 + wg * 64 + lane];
    const float linv = 1.0f / (lsum + l2);
    const size_t orow = ((size_t)b * 2048 + q0 + q5) * 1024 + (size_t)h * 64;
#pragma unroll
    for (int mt = 0; mt < 2; mt++){
#pragma unroll
      for (int g = 0; g < 4; g++){
        bf16x4 o4;
#pragma unroll
        for (int u = 0; u < 4; u++)
          o4[u] = f2b((oacc[mt][g*4 + u] + base[mt*16 + g*4 + u]) * linv);
        *(bf16x4*)(O + orow + mt*32 + g*8 + 4*hh) = o4;
      }
    }
  }
}
#undef STAGE

// ---------------------------------------------------------------------------
extern "C" void kernel_launch(void* const* d_in, const int* in_sizes, int n_in,
                              void* d_out, int out_size, void* d_ws, size_t ws_size,
                              hipStream_t stream) {
  const float* emb  = (const float*)d_in[0];
  const float* ctx  = (const float*)d_in[1];
  const float* Wq   = (const float*)d_in[2];
  const float* Wk   = (const float*)d_in[3];
  const float* Wv   = (const float*)d_in[4];
  const float* Wu   = (const float*)d_in[5];
  const float* bu   = (const float*)d_in[6];
  const float* qn_w = (const float*)d_in[7];
  const float* qn_b = (const float*)d_in[8];
  const float* kn_w = (const float*)d_in[9];
  const float* kn_b = (const float*)d_in[10];
  float* out = (float*)d_out;

  const size_t BIG = (size_t)4096 * 1024;
  const size_t WSZ = (size_t)1024 * 1024;
  short* ws   = (short*)d_ws;
  short* embh = ws;
  short* ctxh = embh + BIG;
  short* Wqh  = ctxh + BIG;
  short* Wkh  = Wqh + WSZ;
  short* Wvh  = Wkh + WSZ;
  short* Wuh  = Wvh + WSZ;
  short* qh   = Wuh + WSZ;
  short* kh   = qh + BIG;
  short* vth  = kh + BIG;    // V^T [inner][token], key-permuted columns
  short* aoh  = vth + BIG;

  cvt6_kernel<<<12288, 256, 0, stream>>>(emb, ctx, Wq, Wk, Wv, Wu,
                                         embh, ctxh, Wqh, Wkh, Wvh, Wuh);

  gemm_qkv_kernel<<<dim3(256, 3), 256, 0, stream>>>(
      embh, ctxh, Wqh, Wkh, Wvh, qh, kh, vth,
      qn_w, qn_b, kn_w, kn_b);

  flash2_kernel<<<dim3(16, 16, 2), 512, 0, stream>>>(qh, kh, vth, aoh);

  gemm_out_kernel<<<dim3(32, 8), 1024, 0, stream>>>(aoh, Wuh, out, bu);
}

// Round 8
// 194.215 us; speedup vs baseline: 5.4933x; 1.0288x over previous
//
#include <hip/hip_runtime.h>

// ============================================================================
// MultiHeadCrossAttention on MI355X (gfx950) — round 8
//   B=2, SQ=SK=2048, H=16, D=64, EMB=CTX=INNER=1024, fp32 in/out.
//
// 4 dispatches:
//   1. cvt6: all fp32->bf16 conversions
//   2. gemm_qkv: 128x64 tiles (1536 blocks = 6/CU), XOR-swizzled LDS,
//      q (softmax scale folded), k (+fused LN), vT (key-permuted cols)
//   3. flash2: 8-wave blocks, 2-way K-split, dual interleaved S^T chains,
//      l computed by ones-A MFMA (no serial VALU chain), O^T=V^T·P^T
//   4. gemm_out: 64x64 tiles (1024 blocks = 4/CU), XOR-swizzled LDS
// ============================================================================

typedef __attribute__((ext_vector_type(8)))  short bf16x8;
typedef __attribute__((ext_vector_type(4)))  short bf16x4;
typedef __attribute__((ext_vector_type(4)))  float f32x4;
typedef __attribute__((ext_vector_type(16))) float f32x16;
typedef __attribute__((ext_vector_type(4)))  unsigned int u32x4;

#define SM_SCALE 0.18033688f   // 0.125 * log2(e), folded into q at LN

typedef __attribute__((address_space(1))) const void cg_void;
typedef __attribute__((address_space(3))) void lds_void_t;

__device__ __forceinline__ void gl_lds16(const void* g, void* l){
  __builtin_amdgcn_global_load_lds((cg_void*)g, (lds_void_t*)l, 16, 0, 0);
}

__device__ __forceinline__ short f2b(float f){
  unsigned int u;
  __builtin_memcpy(&u, &f, 4);
  u += 0x7fffu + ((u >> 16) & 1u);   // round-to-nearest-even
  return (short)(u >> 16);
}

// ---------------------------------------------------------------------------
// Fused fp32 -> bf16 convert of all six inputs (12M elems, 4 per thread).
// ---------------------------------------------------------------------------
__global__ __launch_bounds__(256) void cvt6_kernel(
    const float* __restrict__ emb, const float* __restrict__ ctx,
    const float* __restrict__ Wq, const float* __restrict__ Wk,
    const float* __restrict__ Wv, const float* __restrict__ Wu,
    short* __restrict__ o_emb, short* __restrict__ o_ctx,
    short* __restrict__ o_wq, short* __restrict__ o_wk,
    short* __restrict__ o_wv, short* __restrict__ o_wu)
{
  const long M1 = 1024L * 1024L, M4 = 4L * M1;
  long e = ((long)blockIdx.x * 256 + threadIdx.x) * 4;
  if (e >= 12L * M1) return;
  const float* src; short* dst; long off;
  if      (e <     M4)      { src = emb; dst = o_emb; off = e;           }
  else if (e < 2 * M4)      { src = ctx; dst = o_ctx; off = e - M4;      }
  else if (e < 2 * M4 + M1) { src = Wq;  dst = o_wq;  off = e - 2 * M4;  }
  else if (e < 2 * M4 + 2*M1){src = Wk;  dst = o_wk;  off = e - 2*M4 - M1;}
  else if (e < 2 * M4 + 3*M1){src = Wv;  dst = o_wv;  off = e - 2*M4 - 2*M1;}
  else                      { src = Wu;  dst = o_wu;  off = e - 2*M4 - 3*M1;}
  f32x4 v = *(const f32x4*)(src + off);
  bf16x4 o;
  o[0] = f2b(v[0]); o[1] = f2b(v[1]); o[2] = f2b(v[2]); o[3] = f2b(v[3]);
  *(bf16x4*)(dst + off) = o;
}

// ---------------------------------------------------------------------------
// Fused QKV projections. Grid (512, 3); blockIdx.y = task.
//   task 0: q = (emb@Wq^T -> LN)*SM_SCALE   (bm fastest, x&31)
//   task 1: k = ctx@Wk^T + LN               (bm fastest)
//   task 2: vT = Wv@ctx^T, key-permuted cols (bn fastest, x&63)
// 128x64 tile (M x N), BK=64, 4 waves each 32x64 (2x4 MFMA 16x16x32).
// BN=64 = one head chunk -> LN stays wave-local. XOR-swizzled LDS.
// 24 KB LDS -> ~6 blocks/CU (latency hiding is the point of this shape).
// ---------------------------------------------------------------------------
__global__ __launch_bounds__(256, 5) void gemm_qkv_kernel(
    const short* __restrict__ embh, const short* __restrict__ ctxh,
    const short* __restrict__ Wqh, const short* __restrict__ Wkh,
    const short* __restrict__ Wvh,
    short* __restrict__ qo, short* __restrict__ ko, short* __restrict__ vto,
    const float* __restrict__ qw, const float* __restrict__ qb,
    const float* __restrict__ kw, const float* __restrict__ kb)
{
  const int K = 1024;
  __shared__ short As[128 * 64];   // 16 KB
  __shared__ short Bs[64 * 64];    //  8 KB
  const int tid  = threadIdx.x;
  const int wave = tid >> 6, lane = tid & 63;
  const int quad = lane >> 4, r16 = lane & 15;
  const int wm = wave * 32;

  const int task = blockIdx.y;
  int bn, bm, N;
  const short *A, *B;
  if (task == 2){
    bn = (blockIdx.x & 63) * 64; bm = (blockIdx.x >> 6) * 128; N = 4096;
    A = Wvh; B = ctxh;
  } else {
    bm = (blockIdx.x & 31) * 128; bn = (blockIdx.x >> 5) * 64; N = 1024;
    A = task ? ctxh : embh; B = task ? Wkh : Wqh;
  }

  f32x4 acc[2][4];
#pragma unroll
  for (int i = 0; i < 2; i++)
#pragma unroll
    for (int j = 0; j < 4; j++)
      acc[i][j] = (f32x4){0.f, 0.f, 0.f, 0.f};

  const int sr7 = (lane >> 3) & 7;
  const size_t arow = (size_t)(bm + wave * 8 + (lane >> 3)) * K
                      + (((lane & 7) ^ sr7) * 8);
  const size_t brow = (size_t)(bn + wave * 8 + (lane >> 3)) * K
                      + (((lane & 7) ^ sr7) * 8);
  const int sw = ((quad ^ (r16 & 7)) << 3);

  for (int k0 = 0; k0 < K; k0 += 64){
#pragma unroll
    for (int i = 0; i < 4; i++)
      gl_lds16(A + arow + (size_t)32 * i * K + k0, &As[wave * 512 + i * 2048]);
#pragma unroll
    for (int i = 0; i < 2; i++)
      gl_lds16(B + brow + (size_t)32 * i * K + k0, &Bs[wave * 512 + i * 2048]);
    __syncthreads();
#pragma unroll
    for (int kk = 0; kk < 2; kk++){
      const int off = sw ^ (kk << 5);
      bf16x8 af[2], bq[4];
#pragma unroll
      for (int i = 0; i < 2; i++)
        af[i] = *(const bf16x8*)(&As[(wm + i*16 + r16) * 64 + off]);
#pragma unroll
      for (int j = 0; j < 4; j++)
        bq[j] = *(const bf16x8*)(&Bs[(j*16 + r16) * 64 + off]);
#pragma unroll
      for (int i = 0; i < 2; i++)
#pragma unroll
        for (int j = 0; j < 4; j++)
          acc[i][j] = __builtin_amdgcn_mfma_f32_16x16x32_bf16(af[i], bq[j], acc[i][j], 0, 0, 0);
    }
    __syncthreads();
  }

  if (task < 2){
    short* Ch = task ? ko : qo;
    const float* lw = task ? kw : qw;
    const float* lb = task ? kb : qb;
    const float post = task ? 1.0f : SM_SCALE;   // fold softmax scale into q
    float wv[4], bv[4];
#pragma unroll
    for (int j = 0; j < 4; j++){
      wv[j] = lw[j*16 + r16] * post;
      bv[j] = lb[j*16 + r16] * post;
    }
#pragma unroll
    for (int i = 0; i < 2; i++){
#pragma unroll
      for (int t = 0; t < 4; t++){
        float a[4];
#pragma unroll
        for (int j = 0; j < 4; j++) a[j] = acc[i][j][t];
        float s = a[0] + a[1] + a[2] + a[3];
        s += __shfl_xor(s, 1); s += __shfl_xor(s, 2);
        s += __shfl_xor(s, 4); s += __shfl_xor(s, 8);
        const float mu = s * 0.015625f;
        float d[4], sq = 0.f;
#pragma unroll
        for (int j = 0; j < 4; j++){ d[j] = a[j] - mu; sq += d[j]*d[j]; }
        sq += __shfl_xor(sq, 1); sq += __shfl_xor(sq, 2);
        sq += __shfl_xor(sq, 4); sq += __shfl_xor(sq, 8);
        const float si = rsqrtf(sq * 0.015625f + 1e-5f);
        const size_t row = (size_t)(bm + wm + i*16 + quad*4 + t);
#pragma unroll
        for (int j = 0; j < 4; j++)
          Ch[row * 1024 + (bn + j*16 + r16)] = f2b(d[j] * si * wv[j] + bv[j]);
      }
    }
  } else {
#pragma unroll
    for (int i = 0; i < 2; i++){
#pragma unroll
      for (int j = 0; j < 4; j++){
        // permute token index within its 32-group into PV fragment order
        const int p = (r16 & 3) | ((j & 1) << 2) | (((r16 >> 2) & 1) << 3)
                      | (((r16 >> 3) & 1) << 4);
        const int col = ((bn + j*16 + r16) & ~31) | p;
#pragma unroll
        for (int t = 0; t < 4; t++){
          const size_t row = (size_t)(bm + wm + i*16 + quad*4 + t);
          vto[row * (size_t)N + col] = f2b(acc[i][j][t]);
        }
      }
    }
  }
}

// ---------------------------------------------------------------------------
// out = ao @ Wu^T + bu. M=4096, N=K=1024, fp32 out.
// 64x64 tile, 256 threads, 4 waves 2x2 each 32x32 (2x2 MFMA). 16 KB LDS ->
// grid 1024 blocks = 4 blocks/CU: block-level overlap hides barrier drains.
// XOR-swizzled LDS. Grid (64, 16): bm fastest (same-A blocks share XCD).
// ---------------------------------------------------------------------------
__global__ __launch_bounds__(256, 4) void gemm_out_kernel(
    const short* __restrict__ A, const short* __restrict__ B,
    float* __restrict__ Cf, const float* __restrict__ bias)
{
  const int K = 1024, N = 1024;
  __shared__ short As[64 * 64];   // 8 KB
  __shared__ short Bs[64 * 64];   // 8 KB
  const int tid  = threadIdx.x;
  const int wave = tid >> 6, lane = tid & 63;
  const int quad = lane >> 4, r16 = lane & 15;
  const int wm = (wave >> 1) * 32, wn = (wave & 1) * 32;
  const int bm = blockIdx.x * 64, bn = blockIdx.y * 64;

  f32x4 acc[2][2];
#pragma unroll
  for (int i = 0; i < 2; i++)
#pragma unroll
    for (int j = 0; j < 2; j++)
      acc[i][j] = (f32x4){0.f, 0.f, 0.f, 0.f};

  const int sr7 = (lane >> 3) & 7;
  const size_t arow = (size_t)(bm + wave * 8 + (lane >> 3)) * K
                      + (((lane & 7) ^ sr7) * 8);
  const size_t brow = (size_t)(bn + wave * 8 + (lane >> 3)) * K
                      + (((lane & 7) ^ sr7) * 8);
  const int sw = ((quad ^ (r16 & 7)) << 3);

  for (int k0 = 0; k0 < K; k0 += 64){
#pragma unroll
    for (int i = 0; i < 2; i++){
      gl_lds16(A + arow + (size_t)32 * i * K + k0, &As[wave * 512 + i * 2048]);
      gl_lds16(B + brow + (size_t)32 * i * K + k0, &Bs[wave * 512 + i * 2048]);
    }
    __syncthreads();
#pragma unroll
    for (int kk = 0; kk < 2; kk++){
      const int off = sw ^ (kk << 5);
      bf16x8 af[2], bq[2];
#pragma unroll
      for (int i = 0; i < 2; i++)
        af[i] = *(const bf16x8*)(&As[(wm + i*16 + r16) * 64 + off]);
#pragma unroll
      for (int j = 0; j < 2; j++)
        bq[j] = *(const bf16x8*)(&Bs[(wn + j*16 + r16) * 64 + off]);
#pragma unroll
      for (int i = 0; i < 2; i++)
#pragma unroll
        for (int j = 0; j < 2; j++)
          acc[i][j] = __builtin_amdgcn_mfma_f32_16x16x32_bf16(af[i], bq[j], acc[i][j], 0, 0, 0);
    }
    __syncthreads();
  }

#pragma unroll
  for (int i = 0; i < 2; i++){
#pragma unroll
    for (int j = 0; j < 2; j++){
      const int col = bn + wn + j*16 + r16;
#pragma unroll
      for (int t = 0; t < 4; t++){
        const size_t row = (size_t)(bm + wm + i*16 + quad*4 + t);
        Cf[row * N + col] = acc[i][j][t] + bias[col];
      }
    }
  }
}

// ---------------------------------------------------------------------------
// MFMA flash attention v5 — 8 waves, 2-way K-split, MFMA-computed l.
//   Grid (16 h, 16 qb, 2 b): h innermost -> per-XCD K/V L2 reuse.
//   wave = half*4 + wg. Per half: double-buffered 64-key tiles (XOR-swizzled).
//   Per iter: hoist 8 kf reads, dual interleaved S^T=K·Q^T chains; per s32:
//   exp2 (scale pre-folded into q) -> pack (bit-add + v_perm) -> PV MFMAs
//   plus l-MFMA with constant ones A-operand (no serial VALU sum chain).
//   End: halves combine through LDS (stride-33 floats).
// ---------------------------------------------------------------------------
__global__ __launch_bounds__(512, 4) void flash2_kernel(
    const short* __restrict__ Q, const short* __restrict__ K,
    const short* __restrict__ Vt, short* __restrict__ O)
{
  __shared__ __align__(16) long long smem8[8192];   // 64 KB
  short* Ks  = (short*)smem8;        // 4 bufs x 4096 shorts: [half*2+buf]
  short* Vts = Ks + 16384;
  float* scr = (float*)smem8;        // epilogue reuse

  const int tid = threadIdx.x;
  const int wave = tid >> 6, lane = tid & 63;
  const int half = wave >> 2, wg = wave & 3;
  const int hh = lane >> 5, q5 = lane & 31;
  const int h = blockIdx.x, qb = blockIdx.y, b = blockIdx.z;
  const int q0 = qb * 128 + wg * 32;

  const size_t kbase = ((size_t)b * 2048) * 1024 + (size_t)h * 64;
  const size_t vbase = ((size_t)h * 64) * 4096 + (size_t)b * 2048;

  // Q B-frags: lane holds Q[q0+q5][c*16 + hh*8 + j]  (pre-scaled by SM_SCALE)
  bf16x8 qf[4];
  {
    const size_t qrow = ((size_t)b * 2048 + q0 + q5) * 1024 + (size_t)h * 64;
#pragma unroll
    for (int c = 0; c < 4; c++)
      qf[c] = *(const bf16x8*)(Q + qrow + c * 16 + hh * 8);
  }

  bf16x8 onesf;
#pragma unroll
  for (int j = 0; j < 8; j++) onesf[j] = (short)0x3F80;   // bf16 1.0

  f32x16 oacc[2], oaccl;
#pragma unroll
  for (int t = 0; t < 16; t++){ oacc[0][t] = 0.f; oacc[1][t] = 0.f; oaccl[t] = 0.f; }

  const int srow = lane >> 3;
  const int csrc = ((lane & 7) ^ srow) * 8;
  const int wr0 = wg * 16;

#define STAGE(bufi, kt)                                                         \
  {                                                                             \
    const short* ks = K + kbase + (size_t)((kt) * 64 + wr0 + srow) * 1024 + csrc; \
    const short* vs = Vt + vbase + (size_t)(wr0 + srow) * 4096 + (kt) * 64 + csrc; \
    short* kd = Ks  + (half * 2 + (bufi)) * 4096 + wr0 * 64;                    \
    short* vd = Vts + (half * 2 + (bufi)) * 4096 + wr0 * 64;                    \
    gl_lds16(ks,            kd);                                                \
    gl_lds16(ks + 8 * 1024, kd + 512);                                          \
    gl_lds16(vs,            vd);                                                \
    gl_lds16(vs + 8 * 4096, vd + 512);                                          \
  }

  STAGE(0, half)

  for (int i = 0; i < 16; i++){
    const int buf = i & 1;
    __syncthreads();                         // staging(buf) drained; buf^1 free
    if (i + 1 < 16) STAGE(buf ^ 1, 2 * (i + 1) + half)

    const short* kb_l = Ks  + (half * 2 + buf) * 4096;
    const short* vb_l = Vts + (half * 2 + buf) * 4096;

    // ---- hoist all 8 kf reads; run both 32-key S chains interleaved ----
    bf16x8 kf[2][4];
#pragma unroll
    for (int s32 = 0; s32 < 2; s32++){
      const int key = s32 * 32 + q5;
#pragma unroll
      for (int c = 0; c < 4; c++)
        kf[s32][c] = *(const bf16x8*)(&kb_l[key * 64 + (((2*c + hh) ^ (key & 7)) << 3)]);
    }
    f32x16 sacc[2];
#pragma unroll
    for (int t = 0; t < 16; t++){ sacc[0][t] = 0.f; sacc[1][t] = 0.f; }
#pragma unroll
    for (int c = 0; c < 4; c++){
      sacc[0] = __builtin_amdgcn_mfma_f32_32x32x16_bf16(kf[0][c], qf[c], sacc[0], 0, 0, 0);
      sacc[1] = __builtin_amdgcn_mfma_f32_32x32x16_bf16(kf[1][c], qf[c], sacc[1], 0, 0, 0);
    }

#pragma unroll
    for (int s32 = 0; s32 < 2; s32++){
      // ---- P = exp2(S^T) (scale pre-folded); pack via bit-add + v_perm ----
      unsigned int pu[16];
#pragma unroll
      for (int t = 0; t < 16; t++){
        const float e = __builtin_amdgcn_exp2f(sacc[s32][t]);
        unsigned int u; __builtin_memcpy(&u, &e, 4);
        pu[t] = u + 0x8000u;                 // round into top 16 bits
      }

      // ---- O^T += V^T·P^T ; l += ones·P^T (const-A MFMA, no LDS) ----
#pragma unroll
      for (int c = 0; c < 2; c++){
        u32x4 tmp;
        tmp[0] = __builtin_amdgcn_perm(pu[4*c + 1], pu[4*c + 0], 0x07060302u);
        tmp[1] = __builtin_amdgcn_perm(pu[4*c + 3], pu[4*c + 2], 0x07060302u);
        tmp[2] = __builtin_amdgcn_perm(pu[8 + 4*c + 1], pu[8 + 4*c + 0], 0x07060302u);
        tmp[3] = __builtin_amdgcn_perm(pu[8 + 4*c + 3], pu[8 + 4*c + 2], 0x07060302u);
        bf16x8 pf; __builtin_memcpy(&pf, &tmp, 16);
#pragma unroll
        for (int mt = 0; mt < 2; mt++){
          const int d = mt * 32 + q5;
          bf16x8 vf = *(const bf16x8*)(&vb_l[d * 64 + (((s32*4 + 2*c + hh) ^ (d & 7)) << 3)]);
          oacc[mt] = __builtin_amdgcn_mfma_f32_32x32x16_bf16(vf, pf, oacc[mt], 0, 0, 0);
        }
        oaccl = __builtin_amdgcn_mfma_f32_32x32x16_bf16(onesf, pf, oaccl, 0, 0, 0);
      }
    }
  }

  // ---- combine halves through LDS, then store O[q][d] = O^T / l ----
  // oaccl: every reg holds l(q5) (all 32 output rows identical).
  const float lhalf = oaccl[0];
  __syncthreads();                           // all buffer reads done
  float* base = scr + (wg * 64 + lane) * 33;
  if (half == 1){
#pragma unroll
    for (int t = 0; t < 16; t++){ base[t] = oacc[0][t]; base[16 + t] = oacc[1][t]; }
    scr[8448 + wg * 64 + lane] = lhalf;
  }
  __syncthreads();
  if (half == 0){
    const float l2 = scr[8448 + wg * 64 + lane];
    const float linv = 1.0f / (lhalf + l2);
    const size_t orow = ((size_t)b * 2048 + q0 + q5) * 1024 + (size_t)h * 64;
#pragma unroll
    for (int mt = 0; mt < 2; mt++){
#pragma unroll
      for (int g = 0; g < 4; g++){
        bf16x4 o4;
#pragma unroll
        for (int u = 0; u < 4; u++)
          o4[u] = f2b((oacc[mt][g*4 + u] + base[mt*16 + g*4 + u]) * linv);
        *(bf16x4*)(O + orow + mt*32 + g*8 + 4*hh) = o4;
      }
    }
  }
}
#undef STAGE

// ---------------------------------------------------------------------------
extern "C" void kernel_launch(void* const* d_in, const int* in_sizes, int n_in,
                              void* d_out, int out_size, void* d_ws, size_t ws_size,
                              hipStream_t stream) {
  const float* emb  = (const float*)d_in[0];
  const float* ctx  = (const float*)d_in[1];
  const float* Wq   = (const float*)d_in[2];
  const float* Wk   = (const float*)d_in[3];
  const float* Wv   = (const float*)d_in[4];
  const float* Wu   = (const float*)d_in[5];
  const float* bu   = (const float*)d_in[6];
  const float* qn_w = (const float*)d_in[7];
  const float* qn_b = (const float*)d_in[8];
  const float* kn_w = (const float*)d_in[9];
  const float* kn_b = (const float*)d_in[10];
  float* out = (float*)d_out;

  const size_t BIG = (size_t)4096 * 1024;
  const size_t WSZ = (size_t)1024 * 1024;
  short* ws   = (short*)d_ws;
  short* embh = ws;
  short* ctxh = embh + BIG;
  short* Wqh  = ctxh + BIG;
  short* Wkh  = Wqh + WSZ;
  short* Wvh  = Wkh + WSZ;
  short* Wuh  = Wvh + WSZ;
  short* qh   = Wuh + WSZ;
  short* kh   = qh + BIG;
  short* vth  = kh + BIG;    // V^T [inner][token], key-permuted columns
  short* aoh  = vth + BIG;

  cvt6_kernel<<<12288, 256, 0, stream>>>(emb, ctx, Wq, Wk, Wv, Wu,
                                         embh, ctxh, Wqh, Wkh, Wvh, Wuh);

  gemm_qkv_kernel<<<dim3(512, 3), 256, 0, stream>>>(
      embh, ctxh, Wqh, Wkh, Wvh, qh, kh, vth,
      qn_w, qn_b, kn_w, kn_b);

  flash2_kernel<<<dim3(16, 16, 2), 512, 0, stream>>>(qh, kh, vth, aoh);

  gemm_out_kernel<<<dim3(64, 16), 256, 0, stream>>>(aoh, Wuh, out, bu);
}